// Round 4
// baseline (432.390 us; speedup 1.0000x reference)
//
#include <hip/hip_runtime.h>
#include <hip/hip_bf16.h>
#include <hip/hip_fp16.h>
#include <math.h>

#define DI 1536
#define DM 768
#define DS 16
#define BB 2
#define LL 2048
#define ML (BB*LL)          /* 4096 rows */
#define NCHUNK 16
#define CLEN (LL/NCHUNK)    /* 128 */

using short8  = __attribute__((ext_vector_type(8))) short;
using floatx4 = __attribute__((ext_vector_type(4))) float;

__device__ __forceinline__ float bf2f(__hip_bfloat16 v) { return __bfloat162float(v); }

// ---------------------------------------------------------------------------
// Convert f32 -> bf16, 4 elements/thread. n % 1024 == 0.
// ---------------------------------------------------------------------------
__global__ __launch_bounds__(256) void cvt_f32_bf16(
    const float* __restrict__ s, __hip_bfloat16* __restrict__ d)
{
    int i = (blockIdx.x * 256 + threadIdx.x) * 4;
    float4 v = *reinterpret_cast<const float4*>(s + i);
    __hip_bfloat16 o[4];
    o[0] = __float2bfloat16(v.x); o[1] = __float2bfloat16(v.y);
    o[2] = __float2bfloat16(v.z); o[3] = __float2bfloat16(v.w);
    *reinterpret_cast<uint2*>(d + i) = *reinterpret_cast<const uint2*>(o);
}

// ---------------------------------------------------------------------------
// Transpose f32 (R x C) -> bf16 (C x R). Dims multiples of 32.
// ---------------------------------------------------------------------------
__global__ __launch_bounds__(256) void transpose_f32_bf16(
    const float* __restrict__ src, __hip_bfloat16* __restrict__ dst,
    int R, int C)
{
    __shared__ __hip_bfloat16 tile[32][34];
    int c0 = blockIdx.x * 32, r0 = blockIdx.y * 32;
    int lx = threadIdx.x & 31, ly = threadIdx.x >> 5;   // ly in 0..7
#pragma unroll
    for (int i = 0; i < 4; ++i)
        tile[ly + 8*i][lx] = __float2bfloat16(src[(size_t)(r0 + ly + 8*i) * C + c0 + lx]);
    __syncthreads();
#pragma unroll
    for (int i = 0; i < 4; ++i)
        dst[(size_t)(c0 + ly + 8*i) * R + r0 + lx] = tile[lx][ly + 8*i];
}

// ---------------------------------------------------------------------------
// MFMA bf16 GEMM: C[M,N] = A[M,K] @ B[K,N], B given TRANSPOSED as BT[N,K].
// Block tile 128x128, 4 waves (2x2), each wave 64x64 = 4x4 MFMA 16x16x32 tiles.
// EPI 0: store bf16.  EPI 1: store f16 softplus(acc + bias[col]).  EPI 2: f32.
// ---------------------------------------------------------------------------
template <int EPI>
__global__ __launch_bounds__(256) void gemm_bf16(
    const __hip_bfloat16* __restrict__ A,
    const __hip_bfloat16* __restrict__ BT,
    void* __restrict__ Cout,
    const float* __restrict__ bias,
    int M, int N, int K)
{
    __shared__ __hip_bfloat16 As[128][32];
    __shared__ __hip_bfloat16 Bs[128][32];

    int tid  = threadIdx.x;
    int wave = tid >> 6, lane = tid & 63;
    int quad = lane >> 4, lr = lane & 15;
    int wm = (wave >> 1) * 64, wn = (wave & 1) * 64;
    int bm = blockIdx.x * 128, bn = blockIdx.y * 128;

    floatx4 acc[4][4];
#pragma unroll
    for (int i = 0; i < 4; ++i)
#pragma unroll
        for (int j = 0; j < 4; ++j)
            acc[i][j] = (floatx4){0.f, 0.f, 0.f, 0.f};

    int sr = tid >> 2;              // 0..63
    int sc = (tid & 3) * 8;         // 0,8,16,24

    for (int k0 = 0; k0 < K; k0 += 32) {
        *reinterpret_cast<uint4*>(&As[sr][sc]) =
            *reinterpret_cast<const uint4*>(A + (size_t)(bm + sr) * K + k0 + sc);
        *reinterpret_cast<uint4*>(&As[sr + 64][sc]) =
            *reinterpret_cast<const uint4*>(A + (size_t)(bm + sr + 64) * K + k0 + sc);
        *reinterpret_cast<uint4*>(&Bs[sr][sc]) =
            *reinterpret_cast<const uint4*>(BT + (size_t)(bn + sr) * K + k0 + sc);
        *reinterpret_cast<uint4*>(&Bs[sr + 64][sc]) =
            *reinterpret_cast<const uint4*>(BT + (size_t)(bn + sr + 64) * K + k0 + sc);
        __syncthreads();

        short8 afrag[4], bfrag[4];
#pragma unroll
        for (int i = 0; i < 4; ++i)
            afrag[i] = *reinterpret_cast<const short8*>(&As[wm + i*16 + lr][quad*8]);
#pragma unroll
        for (int j = 0; j < 4; ++j)
            bfrag[j] = *reinterpret_cast<const short8*>(&Bs[wn + j*16 + lr][quad*8]);
#pragma unroll
        for (int i = 0; i < 4; ++i)
#pragma unroll
            for (int j = 0; j < 4; ++j)
                acc[i][j] = __builtin_amdgcn_mfma_f32_16x16x32_bf16(
                    afrag[i], bfrag[j], acc[i][j], 0, 0, 0);
        __syncthreads();
    }

    // epilogue: within 16x16 tile, row = quad*4 + rr, col = lr
#pragma unroll
    for (int i = 0; i < 4; ++i) {
#pragma unroll
        for (int j = 0; j < 4; ++j) {
            int r0 = bm + wm + i*16 + quad*4;
            int c  = bn + wn + j*16 + lr;
#pragma unroll
            for (int rr = 0; rr < 4; ++rr) {
                float v = acc[i][j][rr];
                if (EPI == 0) {
                    ((__hip_bfloat16*)Cout)[(size_t)(r0 + rr) * N + c] = __float2bfloat16(v);
                } else if (EPI == 1) {
                    v += bias[c];
                    float sp = (v > 20.f) ? v : log1pf(__expf(v));
                    ((__half*)Cout)[(size_t)(r0 + rr) * N + c] = __float2half(sp);
                } else {
                    ((float*)Cout)[(size_t)(r0 + rr) * N + c] = v;
                }
            }
        }
    }
}

// ---------------------------------------------------------------------------
// Depthwise causal conv (k=4) + bias + SiLU.  xz bf16, weights f32.
// ---------------------------------------------------------------------------
__global__ __launch_bounds__(256) void conv_silu(
    const __hip_bfloat16* __restrict__ xz,
    const float* __restrict__ Wc,
    const float* __restrict__ bc,
    __hip_bfloat16* __restrict__ xc)
{
    int idx = blockIdx.x * 256 + threadIdx.x;      // over ML*DI
    int d = idx % DI;
    int m = idx / DI;                              // m = b*LL + t
    int t = m % LL;
    float acc = bc[d];
#pragma unroll
    for (int j = 0; j < 4; ++j) {
        int tt = t - 3 + j;
        if (tt >= 0)
            acc += bf2f(xz[(size_t)(m - 3 + j) * (2*DI) + d]) * Wc[d*4 + j];
    }
    float s = acc / (1.f + __expf(-acc));
    xc[idx] = __float2bfloat16(s);
}

// ---------------------------------------------------------------------------
// BC = xc @ W_x  (ML x DI) @ (DI x 32) -> f32.
// ---------------------------------------------------------------------------
__global__ __launch_bounds__(256) void bc_gemm(
    const __hip_bfloat16* __restrict__ xc,
    const float* __restrict__ Wx,
    float* __restrict__ BC)
{
    __shared__ __hip_bfloat16 xs[8][DI];
    int m0 = blockIdx.x * 8;
    const uint4* src = reinterpret_cast<const uint4*>(xc + (size_t)m0 * DI);
    uint4* dst = reinterpret_cast<uint4*>(&xs[0][0]);
    for (int i = threadIdx.x; i < 8*DI/8; i += 256) dst[i] = src[i];
    __syncthreads();
    int mi = threadIdx.x >> 5, n = threadIdx.x & 31;
    float acc = 0.f;
    for (int k = 0; k < DI; ++k)
        acc += bf2f(xs[mi][k]) * Wx[(size_t)k*32 + n];
    BC[(size_t)(m0 + mi) * 32 + n] = acc;
}

// ---------------------------------------------------------------------------
// Chunked scan: phase A (per-chunk from h=0, record prod dA & h_end),
// phase B (combine chunks; hend -> hstart in place),
// phase C (replay with true h0, fuse (y + xc*D) * silu(z), write y OVER xc).
// ---------------------------------------------------------------------------
__global__ __launch_bounds__(256) void scan_phaseA(
    const __half* __restrict__ dt, const __hip_bfloat16* __restrict__ xc,
    const float* __restrict__ BC, const float* __restrict__ A_log,
    float* __restrict__ aprod, float* __restrict__ hend)
{
    int d = blockIdx.x * 256 + threadIdx.x;
    int c = blockIdx.y, b = blockIdx.z;
    float Arow[DS];
#pragma unroll
    for (int n = 0; n < DS; ++n) Arow[n] = -__expf(A_log[d*DS + n]);
    float h[DS], ap[DS];
#pragma unroll
    for (int n = 0; n < DS; ++n) { h[n] = 0.f; ap[n] = 1.f; }
    int t0 = c * CLEN;
    for (int t = t0; t < t0 + CLEN; ++t) {
        size_t row = (size_t)b * LL + t;
        float dtv = __half2float(dt[row * DI + d]);
        float xcv = bf2f(xc[row * DI + d]);
        const float* bc = BC + row * 32;
        float dtx = dtv * xcv;
#pragma unroll
        for (int n = 0; n < DS; ++n) {
            float dA = __expf(dtv * Arow[n]);
            h[n]  = dA * h[n] + bc[n] * dtx;
            ap[n] *= dA;
        }
    }
    size_t o = (((size_t)b * NCHUNK + c) * DI + d) * DS;
#pragma unroll
    for (int n = 0; n < DS; n += 4) {
        *reinterpret_cast<float4*>(aprod + o + n) = make_float4(ap[n], ap[n+1], ap[n+2], ap[n+3]);
        *reinterpret_cast<float4*>(hend  + o + n) = make_float4(h[n],  h[n+1],  h[n+2],  h[n+3]);
    }
}

__global__ __launch_bounds__(256) void scan_phaseB(
    const float* __restrict__ aprod, float* __restrict__ hse)
{
    int idx = blockIdx.x * 256 + threadIdx.x;   // over BB*DI*DS
    int b = idx / (DI*DS);
    int dn = idx % (DI*DS);
    float H = 0.f;
#pragma unroll
    for (int c = 0; c < NCHUNK; ++c) {
        size_t o = ((size_t)b * NCHUNK + c) * DI * DS + dn;
        float a  = aprod[o];
        float he = hse[o];
        hse[o] = H;              // becomes hstart for chunk c
        H = a * H + he;
    }
}

__global__ __launch_bounds__(256) void scan_phaseC(
    const __half* __restrict__ dt, const __hip_bfloat16* __restrict__ xz,
    const float* __restrict__ BC, const float* __restrict__ A_log,
    const float* __restrict__ Dv, const float* __restrict__ hstart,
    __hip_bfloat16* __restrict__ xc_y /* xc in, y out (in place) */)
{
    int d = blockIdx.x * 256 + threadIdx.x;
    int c = blockIdx.y, b = blockIdx.z;
    float Arow[DS];
#pragma unroll
    for (int n = 0; n < DS; ++n) Arow[n] = -__expf(A_log[d*DS + n]);
    float Dd = Dv[d];
    float h[DS];
    size_t o = (((size_t)b * NCHUNK + c) * DI + d) * DS;
#pragma unroll
    for (int n = 0; n < DS; ++n) h[n] = hstart[o + n];
    int t0 = c * CLEN;
    for (int t = t0; t < t0 + CLEN; ++t) {
        size_t row = (size_t)b * LL + t;
        float dtv = __half2float(dt[row * DI + d]);
        float xcv = bf2f(xc_y[row * DI + d]);       // read BEFORE write below
        float zv  = bf2f(xz[row * (2*DI) + DI + d]);
        const float* bc = BC + row * 32;
        float dtx = dtv * xcv;
        float yv = 0.f;
#pragma unroll
        for (int n = 0; n < DS; ++n) {
            float dA = __expf(dtv * Arow[n]);
            h[n] = dA * h[n] + bc[n] * dtx;
            yv += h[n] * bc[DS + n];
        }
        float sig = 1.f / (1.f + __expf(-zv));
        float out = (yv + xcv * Dd) * (zv * sig);
        xc_y[row * DI + d] = __float2bfloat16(out);
    }
}

// ---------------------------------------------------------------------------
extern "C" void kernel_launch(void* const* d_in, const int* in_sizes, int n_in,
                              void* d_out, int out_size, void* d_ws, size_t ws_size,
                              hipStream_t stream)
{
    const float* x      = (const float*)d_in[0];
    const float* W_in   = (const float*)d_in[1];
    const float* W_conv = (const float*)d_in[2];
    const float* b_conv = (const float*)d_in[3];
    const float* W_x    = (const float*)d_in[4];
    const float* W_dt   = (const float*)d_in[5];
    const float* b_dt   = (const float*)d_in[6];
    const float* A_log  = (const float*)d_in[7];
    const float* Dvec   = (const float*)d_in[8];
    const float* W_out  = (const float*)d_in[9];

    // ---- workspace layout (62.65 MiB total, explicit lifetime reuse) ----
    uint8_t* ws = (uint8_t*)d_ws;
    __hip_bfloat16* xz    = (__hip_bfloat16*)(ws);                // 25,165,824  [G1..SC]
    uint8_t*        regA  = ws + 25165824;                        //  9,437,184 shared region
    __hip_bfloat16* winT  = (__hip_bfloat16*)(regA);              //  4,718,592  [T1..G1]
    __hip_bfloat16* wdtT  = (__hip_bfloat16*)(regA + 4718592);    //  4,718,592  [T2..G3]
    float*          aprod = (float*)(regA);                       //  3,145,728  [SA..SB]  (over winT)
    float*          hse   = (float*)(regA + 3145728);             //  3,145,728  [SA..SC]  (over winT/wdtT)
    __hip_bfloat16* woutT = (__hip_bfloat16*)(ws + 34603008);     //  2,359,296  [T3..G4]
    __hip_bfloat16* xcb   = (__hip_bfloat16*)(ws + 36962304);     // 12,582,912  [CONV..SC], y in place [SC..G4]
    uint8_t*        regB  = ws + 49545216;                        // 12,582,912 shared region
    __hip_bfloat16* xbf   = (__hip_bfloat16*)(regB);              //  6,291,456  [CV..G1]   (over dtb head)
    __half*         dtb   = (__half*)(regB);                      // 12,582,912  [G3..SC]
    float*          BC    = (float*)(ws + 62128128);              //    524,288  [BCG..SC]
    // end: 62,652,416 bytes

    // input conversions / weight transposes (f32 -> bf16, B^T layout)
    cvt_f32_bf16<<<(ML*DM)/1024, 256, 0, stream>>>(x, xbf);
    transpose_f32_bf16<<<dim3(2*DI/32, DM/32), 256, 0, stream>>>(W_in,  winT,  DM, 2*DI);
    transpose_f32_bf16<<<dim3(DI/32,   DI/32), 256, 0, stream>>>(W_dt,  wdtT,  DI, DI);
    transpose_f32_bf16<<<dim3(DM/32,   DI/32), 256, 0, stream>>>(W_out, woutT, DI, DM);

    // GEMM1: xz = x @ W_in     (4096 x 3072 x 768)
    gemm_bf16<0><<<dim3(ML/128, (2*DI)/128), 256, 0, stream>>>(xbf, winT, xz, nullptr, ML, 2*DI, DM);

    // conv + SiLU -> xc
    conv_silu<<<(ML*DI)/256, 256, 0, stream>>>(xz, W_conv, b_conv, xcb);

    // BC = xc @ W_x
    bc_gemm<<<ML/8, 256, 0, stream>>>(xcb, W_x, BC);

    // dt = softplus(xc @ W_dt + b_dt) -> f16   (4096 x 1536 x 1536)
    gemm_bf16<1><<<dim3(ML/128, DI/128), 256, 0, stream>>>(xcb, wdtT, dtb, b_dt, ML, DI, DI);

    // chunked scan + fused gating (y written over xcb)
    scan_phaseA<<<dim3(DI/256, NCHUNK, BB), 256, 0, stream>>>(dtb, xcb, BC, A_log, aprod, hse);
    scan_phaseB<<<(BB*DI*DS)/256, 256, 0, stream>>>(aprod, hse);
    scan_phaseC<<<dim3(DI/256, NCHUNK, BB), 256, 0, stream>>>(dtb, xz, BC, A_log, Dvec, hse, xcb);

    // out = y @ W_out          (4096 x 768 x 1536) -> f32 d_out
    gemm_bf16<2><<<dim3(ML/128, DM/128), 256, 0, stream>>>(xcb, woutT, d_out, nullptr, ML, DM, DI);

    (void)in_sizes; (void)n_in; (void)out_size; (void)ws_size;
}

// Round 5
// 380.007 us; speedup vs baseline: 1.1378x; 1.1378x over previous
//
#include <hip/hip_runtime.h>
#include <hip/hip_bf16.h>
#include <hip/hip_fp16.h>
#include <math.h>

#define DI 1536
#define DM 768
#define DS 16
#define BB 2
#define LL 2048
#define ML (BB*LL)          /* 4096 rows */
#define NCHUNK 32
#define CLEN (LL/NCHUNK)    /* 64 */

using short8  = __attribute__((ext_vector_type(8))) short;
using floatx4 = __attribute__((ext_vector_type(4))) float;

__device__ __forceinline__ float bf2f(__hip_bfloat16 v) { return __bfloat162float(v); }

// ---------------------------------------------------------------------------
// Convert f32 -> bf16, 4 elements/thread. n % 1024 == 0.
// ---------------------------------------------------------------------------
__global__ __launch_bounds__(256) void cvt_f32_bf16(
    const float* __restrict__ s, __hip_bfloat16* __restrict__ d)
{
    int i = (blockIdx.x * 256 + threadIdx.x) * 4;
    float4 v = *reinterpret_cast<const float4*>(s + i);
    __hip_bfloat16 o[4];
    o[0] = __float2bfloat16(v.x); o[1] = __float2bfloat16(v.y);
    o[2] = __float2bfloat16(v.z); o[3] = __float2bfloat16(v.w);
    *reinterpret_cast<uint2*>(d + i) = *reinterpret_cast<const uint2*>(o);
}

// ---------------------------------------------------------------------------
// Transpose f32 (R x C) -> bf16 (C x R). Dims multiples of 32.
// ---------------------------------------------------------------------------
__global__ __launch_bounds__(256) void transpose_f32_bf16(
    const float* __restrict__ src, __hip_bfloat16* __restrict__ dst,
    int R, int C)
{
    __shared__ __hip_bfloat16 tile[32][34];
    int c0 = blockIdx.x * 32, r0 = blockIdx.y * 32;
    int lx = threadIdx.x & 31, ly = threadIdx.x >> 5;   // ly in 0..7
#pragma unroll
    for (int i = 0; i < 4; ++i)
        tile[ly + 8*i][lx] = __float2bfloat16(src[(size_t)(r0 + ly + 8*i) * C + c0 + lx]);
    __syncthreads();
#pragma unroll
    for (int i = 0; i < 4; ++i)
        dst[(size_t)(c0 + ly + 8*i) * R + r0 + lx] = tile[lx][ly + 8*i];
}

// ---------------------------------------------------------------------------
// MFMA bf16 GEMM: C[M,N] = A[M,K] @ B[K,N], B given TRANSPOSED as BT[N,K].
// Block tile 128x128, 4 waves (2x2), each wave 64x64 = 4x4 MFMA 16x16x32 tiles.
// EPI 0: store bf16.  EPI 1: store f16 softplus(acc + bias[col]).  EPI 2: f32.
// ---------------------------------------------------------------------------
template <int EPI>
__global__ __launch_bounds__(256) void gemm_bf16(
    const __hip_bfloat16* __restrict__ A,
    const __hip_bfloat16* __restrict__ BT,
    void* __restrict__ Cout,
    const float* __restrict__ bias,
    int M, int N, int K)
{
    __shared__ __hip_bfloat16 As[128][32];
    __shared__ __hip_bfloat16 Bs[128][32];

    int tid  = threadIdx.x;
    int wave = tid >> 6, lane = tid & 63;
    int quad = lane >> 4, lr = lane & 15;
    int wm = (wave >> 1) * 64, wn = (wave & 1) * 64;
    int bm = blockIdx.x * 128, bn = blockIdx.y * 128;

    floatx4 acc[4][4];
#pragma unroll
    for (int i = 0; i < 4; ++i)
#pragma unroll
        for (int j = 0; j < 4; ++j)
            acc[i][j] = (floatx4){0.f, 0.f, 0.f, 0.f};

    int sr = tid >> 2;              // 0..63
    int sc = (tid & 3) * 8;         // 0,8,16,24

    for (int k0 = 0; k0 < K; k0 += 32) {
        *reinterpret_cast<uint4*>(&As[sr][sc]) =
            *reinterpret_cast<const uint4*>(A + (size_t)(bm + sr) * K + k0 + sc);
        *reinterpret_cast<uint4*>(&As[sr + 64][sc]) =
            *reinterpret_cast<const uint4*>(A + (size_t)(bm + sr + 64) * K + k0 + sc);
        *reinterpret_cast<uint4*>(&Bs[sr][sc]) =
            *reinterpret_cast<const uint4*>(BT + (size_t)(bn + sr) * K + k0 + sc);
        *reinterpret_cast<uint4*>(&Bs[sr + 64][sc]) =
            *reinterpret_cast<const uint4*>(BT + (size_t)(bn + sr + 64) * K + k0 + sc);
        __syncthreads();

        short8 afrag[4], bfrag[4];
#pragma unroll
        for (int i = 0; i < 4; ++i)
            afrag[i] = *reinterpret_cast<const short8*>(&As[wm + i*16 + lr][quad*8]);
#pragma unroll
        for (int j = 0; j < 4; ++j)
            bfrag[j] = *reinterpret_cast<const short8*>(&Bs[wn + j*16 + lr][quad*8]);
#pragma unroll
        for (int i = 0; i < 4; ++i)
#pragma unroll
            for (int j = 0; j < 4; ++j)
                acc[i][j] = __builtin_amdgcn_mfma_f32_16x16x32_bf16(
                    afrag[i], bfrag[j], acc[i][j], 0, 0, 0);
        __syncthreads();
    }

    // epilogue: within 16x16 tile, row = quad*4 + rr, col = lr
#pragma unroll
    for (int i = 0; i < 4; ++i) {
#pragma unroll
        for (int j = 0; j < 4; ++j) {
            int r0 = bm + wm + i*16 + quad*4;
            int c  = bn + wn + j*16 + lr;
#pragma unroll
            for (int rr = 0; rr < 4; ++rr) {
                float v = acc[i][j][rr];
                if (EPI == 0) {
                    ((__hip_bfloat16*)Cout)[(size_t)(r0 + rr) * N + c] = __float2bfloat16(v);
                } else if (EPI == 1) {
                    v += bias[c];
                    float sp = (v > 20.f) ? v : log1pf(__expf(v));
                    ((__half*)Cout)[(size_t)(r0 + rr) * N + c] = __float2half(sp);
                } else {
                    ((float*)Cout)[(size_t)(r0 + rr) * N + c] = v;
                }
            }
        }
    }
}

// ---------------------------------------------------------------------------
// Depthwise causal conv (k=4) + bias + SiLU.  xz bf16, weights f32.
// ---------------------------------------------------------------------------
__global__ __launch_bounds__(256) void conv_silu(
    const __hip_bfloat16* __restrict__ xz,
    const float* __restrict__ Wc,
    const float* __restrict__ bc,
    __hip_bfloat16* __restrict__ xc)
{
    int idx = blockIdx.x * 256 + threadIdx.x;      // over ML*DI
    int d = idx % DI;
    int m = idx / DI;                              // m = b*LL + t
    int t = m % LL;
    float acc = bc[d];
#pragma unroll
    for (int j = 0; j < 4; ++j) {
        int tt = t - 3 + j;
        if (tt >= 0)
            acc += bf2f(xz[(size_t)(m - 3 + j) * (2*DI) + d]) * Wc[d*4 + j];
    }
    float s = acc / (1.f + __expf(-acc));
    xc[idx] = __float2bfloat16(s);
}

// ---------------------------------------------------------------------------
// BC = xc @ W_x  (ML x DI) @ (DI x 32) -> f32.
// ---------------------------------------------------------------------------
__global__ __launch_bounds__(256) void bc_gemm(
    const __hip_bfloat16* __restrict__ xc,
    const float* __restrict__ Wx,
    float* __restrict__ BC)
{
    __shared__ __hip_bfloat16 xs[8][DI];
    int m0 = blockIdx.x * 8;
    const uint4* src = reinterpret_cast<const uint4*>(xc + (size_t)m0 * DI);
    uint4* dst = reinterpret_cast<uint4*>(&xs[0][0]);
    for (int i = threadIdx.x; i < 8*DI/8; i += 256) dst[i] = src[i];
    __syncthreads();
    int mi = threadIdx.x >> 5, n = threadIdx.x & 31;
    float acc = 0.f;
    for (int k = 0; k < DI; ++k)
        acc += bf2f(xs[mi][k]) * Wx[(size_t)k*32 + n];
    BC[(size_t)(m0 + mi) * 32 + n] = acc;
}

// ---------------------------------------------------------------------------
// Chunked scan, thread-per-(d, 4 states).  32 chunks x 64 steps.
// phase A: per chunk from h=0, record prod(dA), h_end (f16).
// phase B: combine across chunks (hend -> hstart, in place).
// phase C: replay with true h0; y = sum_n h*C (shfl-reduce over 4 lanes);
//          fuse (y + xc*D)*silu(z); write y OVER xc.
// ---------------------------------------------------------------------------
__global__ __launch_bounds__(256) void scan_phaseA(
    const __half* __restrict__ dt, const __hip_bfloat16* __restrict__ xc,
    const float* __restrict__ BC, const float* __restrict__ A_log,
    __half* __restrict__ aprod, __half* __restrict__ hend)
{
    int idx = blockIdx.x * 256 + threadIdx.x;   // over DI*4 = 6144
    int q = idx & 3, d = idx >> 2;
    int c = blockIdx.y, b = blockIdx.z;
    float A4[4], h[4], ap[4];
#pragma unroll
    for (int j = 0; j < 4; ++j) {
        A4[j] = -__expf(A_log[d*DS + q*4 + j]);
        h[j] = 0.f; ap[j] = 1.f;
    }
    int t0 = c * CLEN;
    for (int t = t0; t < t0 + CLEN; ++t) {
        size_t row = (size_t)b * LL + t;
        float dtv = __half2float(dt[row * DI + d]);
        float xcv = bf2f(xc[row * DI + d]);
        float4 B4 = *reinterpret_cast<const float4*>(BC + row * 32 + q*4);
        float dtx = dtv * xcv;
#pragma unroll
        for (int j = 0; j < 4; ++j) {
            float dA = __expf(dtv * A4[j]);
            h[j]  = dA * h[j] + ((const float*)&B4)[j] * dtx;
            ap[j] *= dA;
        }
    }
    size_t o = (((size_t)b * NCHUNK + c) * DI + d) * DS + q*4;
    __half oa[4], oh[4];
#pragma unroll
    for (int j = 0; j < 4; ++j) { oa[j] = __float2half(ap[j]); oh[j] = __float2half(h[j]); }
    *reinterpret_cast<uint2*>(aprod + o) = *reinterpret_cast<const uint2*>(oa);
    *reinterpret_cast<uint2*>(hend  + o) = *reinterpret_cast<const uint2*>(oh);
}

__global__ __launch_bounds__(256) void scan_phaseB(
    const __half* __restrict__ aprod, __half* __restrict__ hse)
{
    int idx = blockIdx.x * 256 + threadIdx.x;   // over BB*DI*DS
    int b = idx / (DI*DS);
    int dn = idx % (DI*DS);
    float H = 0.f;
#pragma unroll
    for (int c = 0; c < NCHUNK; ++c) {
        size_t o = ((size_t)b * NCHUNK + c) * (DI*DS) + dn;
        float a  = __half2float(aprod[o]);
        float he = __half2float(hse[o]);
        hse[o] = __float2half(H);          // becomes hstart for chunk c
        H = a * H + he;
    }
}

__global__ __launch_bounds__(256) void scan_phaseC(
    const __half* __restrict__ dt, const __hip_bfloat16* __restrict__ xz,
    const float* __restrict__ BC, const float* __restrict__ A_log,
    const float* __restrict__ Dv, const __half* __restrict__ hstart,
    __hip_bfloat16* __restrict__ xc_y /* xc in, y out (in place) */)
{
    int idx = blockIdx.x * 256 + threadIdx.x;   // over DI*4 = 6144
    int q = idx & 3, d = idx >> 2;
    int c = blockIdx.y, b = blockIdx.z;
    float A4[4], h[4];
#pragma unroll
    for (int j = 0; j < 4; ++j)
        A4[j] = -__expf(A_log[d*DS + q*4 + j]);
    float Dd = Dv[d];
    size_t o = (((size_t)b * NCHUNK + c) * DI + d) * DS + q*4;
    {
        uint2 tmp = *reinterpret_cast<const uint2*>(hstart + o);
        const __half* hp = reinterpret_cast<const __half*>(&tmp);
#pragma unroll
        for (int j = 0; j < 4; ++j) h[j] = __half2float(hp[j]);
    }
    int t0 = c * CLEN;
    for (int t = t0; t < t0 + CLEN; ++t) {
        size_t row = (size_t)b * LL + t;
        float dtv = __half2float(dt[row * DI + d]);
        float xcv = bf2f(xc_y[row * DI + d]);       // read BEFORE the masked write
        float zv  = bf2f(xz[row * (2*DI) + DI + d]);
        float4 B4 = *reinterpret_cast<const float4*>(BC + row * 32 + q*4);
        float4 C4 = *reinterpret_cast<const float4*>(BC + row * 32 + 16 + q*4);
        float dtx = dtv * xcv;
        float ys = 0.f;
#pragma unroll
        for (int j = 0; j < 4; ++j) {
            float dA = __expf(dtv * A4[j]);
            h[j] = dA * h[j] + ((const float*)&B4)[j] * dtx;
            ys = fmaf(h[j], ((const float*)&C4)[j], ys);
        }
        ys += __shfl_xor(ys, 1);
        ys += __shfl_xor(ys, 2);
        if (q == 0) {
            float sig = 1.f / (1.f + __expf(-zv));
            float out = (ys + xcv * Dd) * (zv * sig);
            xc_y[row * DI + d] = __float2bfloat16(out);
        }
    }
}

// ---------------------------------------------------------------------------
extern "C" void kernel_launch(void* const* d_in, const int* in_sizes, int n_in,
                              void* d_out, int out_size, void* d_ws, size_t ws_size,
                              hipStream_t stream)
{
    const float* x      = (const float*)d_in[0];
    const float* W_in   = (const float*)d_in[1];
    const float* W_conv = (const float*)d_in[2];
    const float* b_conv = (const float*)d_in[3];
    const float* W_x    = (const float*)d_in[4];
    const float* W_dt   = (const float*)d_in[5];
    const float* b_dt   = (const float*)d_in[6];
    const float* A_log  = (const float*)d_in[7];
    const float* Dvec   = (const float*)d_in[8];
    const float* W_out  = (const float*)d_in[9];

    // ---- workspace layout (62.65 MiB total, explicit lifetime reuse) ----
    uint8_t* ws = (uint8_t*)d_ws;
    __hip_bfloat16* xz    = (__hip_bfloat16*)(ws);                // 25,165,824  [G1..SC]
    uint8_t*        regA  = ws + 25165824;                        //  9,437,184 shared region
    __hip_bfloat16* winT  = (__hip_bfloat16*)(regA);              //  4,718,592  [T1..G1]
    __hip_bfloat16* wdtT  = (__hip_bfloat16*)(regA + 4718592);    //  4,718,592  [T2..G3]
    __half*         aprod = (__half*)(regA);                      //  3,145,728  [SA..SB]  (over winT)
    __half*         hse   = (__half*)(regA + 3145728);            //  3,145,728  [SA..SC]  (over winT/wdtT)
    __hip_bfloat16* woutT = (__hip_bfloat16*)(ws + 34603008);     //  2,359,296  [T3..G4]
    __hip_bfloat16* xcb   = (__hip_bfloat16*)(ws + 36962304);     // 12,582,912  [CONV..SC], y in place [SC..G4]
    uint8_t*        regB  = ws + 49545216;                        // 12,582,912 shared region
    __hip_bfloat16* xbf   = (__hip_bfloat16*)(regB);              //  6,291,456  [CV..G1]   (over dtb head)
    __half*         dtb   = (__half*)(regB);                      // 12,582,912  [G3..SC]
    float*          BC    = (float*)(ws + 62128128);              //    524,288  [BCG..SC]
    // end: 62,652,416 bytes

    // input conversions / weight transposes (f32 -> bf16, B^T layout)
    cvt_f32_bf16<<<(ML*DM)/1024, 256, 0, stream>>>(x, xbf);
    transpose_f32_bf16<<<dim3(2*DI/32, DM/32), 256, 0, stream>>>(W_in,  winT,  DM, 2*DI);
    transpose_f32_bf16<<<dim3(DI/32,   DI/32), 256, 0, stream>>>(W_dt,  wdtT,  DI, DI);
    transpose_f32_bf16<<<dim3(DM/32,   DI/32), 256, 0, stream>>>(W_out, woutT, DI, DM);

    // GEMM1: xz = x @ W_in     (4096 x 3072 x 768)
    gemm_bf16<0><<<dim3(ML/128, (2*DI)/128), 256, 0, stream>>>(xbf, winT, xz, nullptr, ML, 2*DI, DM);

    // conv + SiLU -> xc
    conv_silu<<<(ML*DI)/256, 256, 0, stream>>>(xz, W_conv, b_conv, xcb);

    // BC = xc @ W_x
    bc_gemm<<<ML/8, 256, 0, stream>>>(xcb, W_x, BC);

    // dt = softplus(xc @ W_dt + b_dt) -> f16   (4096 x 1536 x 1536)
    gemm_bf16<1><<<dim3(ML/128, DI/128), 256, 0, stream>>>(xcb, wdtT, dtb, b_dt, ML, DI, DI);

    // chunked scan + fused gating (y written over xcb)
    scan_phaseA<<<dim3(DI*4/256, NCHUNK, BB), 256, 0, stream>>>(dtb, xcb, BC, A_log, aprod, hse);
    scan_phaseB<<<(BB*DI*DS)/256, 256, 0, stream>>>(aprod, hse);
    scan_phaseC<<<dim3(DI*4/256, NCHUNK, BB), 256, 0, stream>>>(dtb, xz, BC, A_log, Dvec, hse, xcb);

    // out = y @ W_out          (4096 x 768 x 1536) -> f32 d_out
    gemm_bf16<2><<<dim3(ML/128, DM/128), 256, 0, stream>>>(xcb, woutT, d_out, nullptr, ML, DM, DI);

    (void)in_sizes; (void)n_in; (void)out_size; (void)ws_size;
}

// Round 6
// 379.266 us; speedup vs baseline: 1.1401x; 1.0020x over previous
//
#include <hip/hip_runtime.h>
#include <hip/hip_bf16.h>
#include <hip/hip_fp16.h>
#include <math.h>

#define DI 1536
#define DM 768
#define DS 16
#define BB 2
#define LL 2048
#define ML (BB*LL)          /* 4096 rows */
#define NCHUNK 32
#define CLEN (LL/NCHUNK)    /* 64 */

using short8  = __attribute__((ext_vector_type(8))) short;
using floatx4 = __attribute__((ext_vector_type(4))) float;

__device__ __forceinline__ float bf2f(__hip_bfloat16 v) { return __bfloat162float(v); }

// async global->LDS copy, 16 B per lane. LDS dest must be lane-contiguous:
// HW uses readfirstlane(lds)+lane*16 (m104/m108).
__device__ __forceinline__ void async_cp16(const void* g, void* l)
{
    __builtin_amdgcn_global_load_lds(
        (const __attribute__((address_space(1))) unsigned int*)g,
        (__attribute__((address_space(3))) unsigned int*)l,
        16, 0, 0);
}

// ---------------------------------------------------------------------------
// Convert f32 -> bf16, 4 elements/thread. n % 1024 == 0.
// ---------------------------------------------------------------------------
__global__ __launch_bounds__(256) void cvt_f32_bf16(
    const float* __restrict__ s, __hip_bfloat16* __restrict__ d)
{
    int i = (blockIdx.x * 256 + threadIdx.x) * 4;
    float4 v = *reinterpret_cast<const float4*>(s + i);
    __hip_bfloat16 o[4];
    o[0] = __float2bfloat16(v.x); o[1] = __float2bfloat16(v.y);
    o[2] = __float2bfloat16(v.z); o[3] = __float2bfloat16(v.w);
    *reinterpret_cast<uint2*>(d + i) = *reinterpret_cast<const uint2*>(o);
}

// ---------------------------------------------------------------------------
// Transpose f32 (R x C) -> bf16 (C x R). Dims multiples of 32.
// ---------------------------------------------------------------------------
__global__ __launch_bounds__(256) void transpose_f32_bf16(
    const float* __restrict__ src, __hip_bfloat16* __restrict__ dst,
    int R, int C)
{
    __shared__ __hip_bfloat16 tile[32][34];
    int c0 = blockIdx.x * 32, r0 = blockIdx.y * 32;
    int lx = threadIdx.x & 31, ly = threadIdx.x >> 5;   // ly in 0..7
#pragma unroll
    for (int i = 0; i < 4; ++i)
        tile[ly + 8*i][lx] = __float2bfloat16(src[(size_t)(r0 + ly + 8*i) * C + c0 + lx]);
    __syncthreads();
#pragma unroll
    for (int i = 0; i < 4; ++i)
        dst[(size_t)(c0 + ly + 8*i) * R + r0 + lx] = tile[lx][ly + 8*i];
}

// ---------------------------------------------------------------------------
// MFMA bf16 GEMM: C[M,N] = A[M,K] @ B[K,N], B given TRANSPOSED as BT[N,K].
// Block tile 128x128, 4 waves (2x2), each wave 64x64 = 4x4 MFMA 16x16x32 tiles.
// Staging: global_load_lds width=16 (m97 ladder step).
// EPI 0: store bf16.  EPI 1: store f16 softplus(acc + bias[col]).  EPI 2: f32.
// ---------------------------------------------------------------------------
template <int EPI>
__global__ __launch_bounds__(256) void gemm_bf16(
    const __hip_bfloat16* __restrict__ A,
    const __hip_bfloat16* __restrict__ BT,
    void* __restrict__ Cout,
    const float* __restrict__ bias,
    int M, int N, int K)
{
    __shared__ __hip_bfloat16 As[128][32];   // byte offset of As[sr][sc] = tid*16
    __shared__ __hip_bfloat16 Bs[128][32];

    int tid  = threadIdx.x;
    int wave = tid >> 6, lane = tid & 63;
    int quad = lane >> 4, lr = lane & 15;
    int wm = (wave >> 1) * 64, wn = (wave & 1) * 64;
    int bm = blockIdx.x * 128, bn = blockIdx.y * 128;

    floatx4 acc[4][4];
#pragma unroll
    for (int i = 0; i < 4; ++i)
#pragma unroll
        for (int j = 0; j < 4; ++j)
            acc[i][j] = (floatx4){0.f, 0.f, 0.f, 0.f};

    int sr = tid >> 2;              // 0..63
    int sc = (tid & 3) * 8;         // 0,8,16,24

    const __hip_bfloat16* gA0 = A  + (size_t)(bm + sr)      * K + sc;
    const __hip_bfloat16* gA1 = A  + (size_t)(bm + sr + 64) * K + sc;
    const __hip_bfloat16* gB0 = BT + (size_t)(bn + sr)      * K + sc;
    const __hip_bfloat16* gB1 = BT + (size_t)(bn + sr + 64) * K + sc;
    __hip_bfloat16* lA0 = &As[sr][sc];
    __hip_bfloat16* lA1 = &As[sr + 64][sc];
    __hip_bfloat16* lB0 = &Bs[sr][sc];
    __hip_bfloat16* lB1 = &Bs[sr + 64][sc];

    for (int k0 = 0; k0 < K; k0 += 32) {
        async_cp16(gA0 + k0, lA0);
        async_cp16(gA1 + k0, lA1);
        async_cp16(gB0 + k0, lB0);
        async_cp16(gB1 + k0, lB1);
        __syncthreads();

        short8 afrag[4], bfrag[4];
#pragma unroll
        for (int i = 0; i < 4; ++i)
            afrag[i] = *reinterpret_cast<const short8*>(&As[wm + i*16 + lr][quad*8]);
#pragma unroll
        for (int j = 0; j < 4; ++j)
            bfrag[j] = *reinterpret_cast<const short8*>(&Bs[wn + j*16 + lr][quad*8]);
#pragma unroll
        for (int i = 0; i < 4; ++i)
#pragma unroll
            for (int j = 0; j < 4; ++j)
                acc[i][j] = __builtin_amdgcn_mfma_f32_16x16x32_bf16(
                    afrag[i], bfrag[j], acc[i][j], 0, 0, 0);
        __syncthreads();
    }

    // epilogue: within 16x16 tile, row = quad*4 + rr, col = lr
#pragma unroll
    for (int i = 0; i < 4; ++i) {
#pragma unroll
        for (int j = 0; j < 4; ++j) {
            int r0 = bm + wm + i*16 + quad*4;
            int c  = bn + wn + j*16 + lr;
#pragma unroll
            for (int rr = 0; rr < 4; ++rr) {
                float v = acc[i][j][rr];
                if (EPI == 0) {
                    ((__hip_bfloat16*)Cout)[(size_t)(r0 + rr) * N + c] = __float2bfloat16(v);
                } else if (EPI == 1) {
                    v += bias[c];
                    float sp = (v > 20.f) ? v : log1pf(__expf(v));
                    ((__half*)Cout)[(size_t)(r0 + rr) * N + c] = __float2half(sp);
                } else {
                    ((float*)Cout)[(size_t)(r0 + rr) * N + c] = v;
                }
            }
        }
    }
}

// ---------------------------------------------------------------------------
// Depthwise causal conv (k=4) + bias + SiLU.  xz bf16, weights f32.
// ---------------------------------------------------------------------------
__global__ __launch_bounds__(256) void conv_silu(
    const __hip_bfloat16* __restrict__ xz,
    const float* __restrict__ Wc,
    const float* __restrict__ bc,
    __hip_bfloat16* __restrict__ xc)
{
    int idx = blockIdx.x * 256 + threadIdx.x;      // over ML*DI
    int d = idx % DI;
    int m = idx / DI;                              // m = b*LL + t
    int t = m % LL;
    float acc = bc[d];
#pragma unroll
    for (int j = 0; j < 4; ++j) {
        int tt = t - 3 + j;
        if (tt >= 0)
            acc += bf2f(xz[(size_t)(m - 3 + j) * (2*DI) + d]) * Wc[d*4 + j];
    }
    float s = acc / (1.f + __expf(-acc));
    xc[idx] = __float2bfloat16(s);
}

// ---------------------------------------------------------------------------
// BC = xc @ W_x  (ML x DI) @ (DI x 32) -> f32.
// ---------------------------------------------------------------------------
__global__ __launch_bounds__(256) void bc_gemm(
    const __hip_bfloat16* __restrict__ xc,
    const float* __restrict__ Wx,
    float* __restrict__ BC)
{
    __shared__ __hip_bfloat16 xs[8][DI];
    int m0 = blockIdx.x * 8;
    const uint4* src = reinterpret_cast<const uint4*>(xc + (size_t)m0 * DI);
    uint4* dst = reinterpret_cast<uint4*>(&xs[0][0]);
    for (int i = threadIdx.x; i < 8*DI/8; i += 256) dst[i] = src[i];
    __syncthreads();
    int mi = threadIdx.x >> 5, n = threadIdx.x & 31;
    float acc = 0.f;
    for (int k = 0; k < DI; ++k)
        acc += bf2f(xs[mi][k]) * Wx[(size_t)k*32 + n];
    BC[(size_t)(m0 + mi) * 32 + n] = acc;
}

// ---------------------------------------------------------------------------
// Chunked scan, thread-per-(d, 4 states).  32 chunks x 64 steps.
// ---------------------------------------------------------------------------
__global__ __launch_bounds__(256) void scan_phaseA(
    const __half* __restrict__ dt, const __hip_bfloat16* __restrict__ xc,
    const float* __restrict__ BC, const float* __restrict__ A_log,
    __half* __restrict__ aprod, __half* __restrict__ hend)
{
    int idx = blockIdx.x * 256 + threadIdx.x;   // over DI*4 = 6144
    int q = idx & 3, d = idx >> 2;
    int c = blockIdx.y, b = blockIdx.z;
    float A4[4], h[4], ap[4];
#pragma unroll
    for (int j = 0; j < 4; ++j) {
        A4[j] = -__expf(A_log[d*DS + q*4 + j]);
        h[j] = 0.f; ap[j] = 1.f;
    }
    int t0 = c * CLEN;
    for (int t = t0; t < t0 + CLEN; ++t) {
        size_t row = (size_t)b * LL + t;
        float dtv = __half2float(dt[row * DI + d]);
        float xcv = bf2f(xc[row * DI + d]);
        float4 B4 = *reinterpret_cast<const float4*>(BC + row * 32 + q*4);
        float dtx = dtv * xcv;
#pragma unroll
        for (int j = 0; j < 4; ++j) {
            float dA = __expf(dtv * A4[j]);
            h[j]  = dA * h[j] + ((const float*)&B4)[j] * dtx;
            ap[j] *= dA;
        }
    }
    size_t o = (((size_t)b * NCHUNK + c) * DI + d) * DS + q*4;
    __half oa[4], oh[4];
#pragma unroll
    for (int j = 0; j < 4; ++j) { oa[j] = __float2half(ap[j]); oh[j] = __float2half(h[j]); }
    *reinterpret_cast<uint2*>(aprod + o) = *reinterpret_cast<const uint2*>(oa);
    *reinterpret_cast<uint2*>(hend  + o) = *reinterpret_cast<const uint2*>(oh);
}

__global__ __launch_bounds__(256) void scan_phaseB(
    const __half* __restrict__ aprod, __half* __restrict__ hse)
{
    int idx = blockIdx.x * 256 + threadIdx.x;   // over BB*DI*DS
    int b = idx / (DI*DS);
    int dn = idx % (DI*DS);
    float H = 0.f;
#pragma unroll
    for (int c = 0; c < NCHUNK; ++c) {
        size_t o = ((size_t)b * NCHUNK + c) * (DI*DS) + dn;
        float a  = __half2float(aprod[o]);
        float he = __half2float(hse[o]);
        hse[o] = __float2half(H);          // becomes hstart for chunk c
        H = a * H + he;
    }
}

__global__ __launch_bounds__(256) void scan_phaseC(
    const __half* __restrict__ dt, const __hip_bfloat16* __restrict__ xz,
    const float* __restrict__ BC, const float* __restrict__ A_log,
    const float* __restrict__ Dv, const __half* __restrict__ hstart,
    __hip_bfloat16* __restrict__ xc_y /* xc in, y out (in place) */)
{
    int idx = blockIdx.x * 256 + threadIdx.x;   // over DI*4 = 6144
    int q = idx & 3, d = idx >> 2;
    int c = blockIdx.y, b = blockIdx.z;
    float A4[4], h[4];
#pragma unroll
    for (int j = 0; j < 4; ++j)
        A4[j] = -__expf(A_log[d*DS + q*4 + j]);
    float Dd = Dv[d];
    size_t o = (((size_t)b * NCHUNK + c) * DI + d) * DS + q*4;
    {
        uint2 tmp = *reinterpret_cast<const uint2*>(hstart + o);
        const __half* hp = reinterpret_cast<const __half*>(&tmp);
#pragma unroll
        for (int j = 0; j < 4; ++j) h[j] = __half2float(hp[j]);
    }
    int t0 = c * CLEN;
    for (int t = t0; t < t0 + CLEN; ++t) {
        size_t row = (size_t)b * LL + t;
        float dtv = __half2float(dt[row * DI + d]);
        float xcv = bf2f(xc_y[row * DI + d]);       // read BEFORE the masked write
        float zv  = bf2f(xz[row * (2*DI) + DI + d]);
        float4 B4 = *reinterpret_cast<const float4*>(BC + row * 32 + q*4);
        float4 C4 = *reinterpret_cast<const float4*>(BC + row * 32 + 16 + q*4);
        float dtx = dtv * xcv;
        float ys = 0.f;
#pragma unroll
        for (int j = 0; j < 4; ++j) {
            float dA = __expf(dtv * A4[j]);
            h[j] = dA * h[j] + ((const float*)&B4)[j] * dtx;
            ys = fmaf(h[j], ((const float*)&C4)[j], ys);
        }
        ys += __shfl_xor(ys, 1);
        ys += __shfl_xor(ys, 2);
        if (q == 0) {
            float sig = 1.f / (1.f + __expf(-zv));
            float out = (ys + xcv * Dd) * (zv * sig);
            xc_y[row * DI + d] = __float2bfloat16(out);
        }
    }
}

// ---------------------------------------------------------------------------
extern "C" void kernel_launch(void* const* d_in, const int* in_sizes, int n_in,
                              void* d_out, int out_size, void* d_ws, size_t ws_size,
                              hipStream_t stream)
{
    const float* x      = (const float*)d_in[0];
    const float* W_in   = (const float*)d_in[1];
    const float* W_conv = (const float*)d_in[2];
    const float* b_conv = (const float*)d_in[3];
    const float* W_x    = (const float*)d_in[4];
    const float* W_dt   = (const float*)d_in[5];
    const float* b_dt   = (const float*)d_in[6];
    const float* A_log  = (const float*)d_in[7];
    const float* Dvec   = (const float*)d_in[8];
    const float* W_out  = (const float*)d_in[9];

    // ---- workspace layout (62.65 MiB total, explicit lifetime reuse) ----
    uint8_t* ws = (uint8_t*)d_ws;
    __hip_bfloat16* xz    = (__hip_bfloat16*)(ws);                // 25,165,824  [G1..SC]
    uint8_t*        regA  = ws + 25165824;                        //  9,437,184 shared region
    __hip_bfloat16* winT  = (__hip_bfloat16*)(regA);              //  4,718,592  [T1..G1]
    __hip_bfloat16* wdtT  = (__hip_bfloat16*)(regA + 4718592);    //  4,718,592  [T2..G3]
    __half*         aprod = (__half*)(regA);                      //  3,145,728  [SA..SB]  (over winT)
    __half*         hse   = (__half*)(regA + 3145728);            //  3,145,728  [SA..SC]  (over winT/wdtT)
    __hip_bfloat16* woutT = (__hip_bfloat16*)(ws + 34603008);     //  2,359,296  [T3..G4]
    __hip_bfloat16* xcb   = (__hip_bfloat16*)(ws + 36962304);     // 12,582,912  [CONV..SC], y in place [SC..G4]
    uint8_t*        regB  = ws + 49545216;                        // 12,582,912 shared region
    __hip_bfloat16* xbf   = (__hip_bfloat16*)(regB);              //  6,291,456  [CV..G1]   (over dtb head)
    __half*         dtb   = (__half*)(regB);                      // 12,582,912  [G3..SC]
    float*          BC    = (float*)(ws + 62128128);              //    524,288  [BCG..SC]
    // end: 62,652,416 bytes

    // input conversions / weight transposes (f32 -> bf16, B^T layout)
    cvt_f32_bf16<<<(ML*DM)/1024, 256, 0, stream>>>(x, xbf);
    transpose_f32_bf16<<<dim3(2*DI/32, DM/32), 256, 0, stream>>>(W_in,  winT,  DM, 2*DI);
    transpose_f32_bf16<<<dim3(DI/32,   DI/32), 256, 0, stream>>>(W_dt,  wdtT,  DI, DI);
    transpose_f32_bf16<<<dim3(DM/32,   DI/32), 256, 0, stream>>>(W_out, woutT, DI, DM);

    // GEMM1: xz = x @ W_in     (4096 x 3072 x 768)
    gemm_bf16<0><<<dim3(ML/128, (2*DI)/128), 256, 0, stream>>>(xbf, winT, xz, nullptr, ML, 2*DI, DM);

    // conv + SiLU -> xc
    conv_silu<<<(ML*DI)/256, 256, 0, stream>>>(xz, W_conv, b_conv, xcb);

    // BC = xc @ W_x
    bc_gemm<<<ML/8, 256, 0, stream>>>(xcb, W_x, BC);

    // dt = softplus(xc @ W_dt + b_dt) -> f16   (4096 x 1536 x 1536)
    gemm_bf16<1><<<dim3(ML/128, DI/128), 256, 0, stream>>>(xcb, wdtT, dtb, b_dt, ML, DI, DI);

    // chunked scan + fused gating (y written over xcb)
    scan_phaseA<<<dim3(DI*4/256, NCHUNK, BB), 256, 0, stream>>>(dtb, xcb, BC, A_log, aprod, hse);
    scan_phaseB<<<(BB*DI*DS)/256, 256, 0, stream>>>(aprod, hse);
    scan_phaseC<<<dim3(DI*4/256, NCHUNK, BB), 256, 0, stream>>>(dtb, xz, BC, A_log, Dvec, hse, xcb);

    // out = y @ W_out          (4096 x 768 x 1536) -> f32 d_out
    gemm_bf16<2><<<dim3(ML/128, DM/128), 256, 0, stream>>>(xcb, woutT, d_out, nullptr, ML, DM, DI);

    (void)in_sizes; (void)n_in; (void)out_size; (void)ws_size;
}

// Round 7
// 354.535 us; speedup vs baseline: 1.2196x; 1.0698x over previous
//
#include <hip/hip_runtime.h>
#include <hip/hip_bf16.h>
#include <hip/hip_fp16.h>
#include <math.h>

#define DI 1536
#define DM 768
#define DS 16
#define BB 2
#define LL 2048
#define ML (BB*LL)          /* 4096 rows */
#define NCHUNK 32
#define CLEN (LL/NCHUNK)    /* 64 */
#define NDT 1664            /* dt-GEMM tiled N: 1536 dt + 32 BC + 96 discard */

using short8  = __attribute__((ext_vector_type(8))) short;
using floatx4 = __attribute__((ext_vector_type(4))) float;

__device__ __forceinline__ float bf2f(__hip_bfloat16 v) { return __bfloat162float(v); }

// async global->LDS copy, 16 B per lane (LDS dest lane-contiguous).
__device__ __forceinline__ void async_cp16(const void* g, void* l)
{
    __builtin_amdgcn_global_load_lds(
        (const __attribute__((address_space(1))) unsigned int*)g,
        (__attribute__((address_space(3))) unsigned int*)l,
        16, 0, 0);
}

// ---------------------------------------------------------------------------
__global__ __launch_bounds__(256) void cvt_f32_bf16(
    const float* __restrict__ s, __hip_bfloat16* __restrict__ d)
{
    int i = (blockIdx.x * 256 + threadIdx.x) * 4;
    float4 v = *reinterpret_cast<const float4*>(s + i);
    __hip_bfloat16 o[4];
    o[0] = __float2bfloat16(v.x); o[1] = __float2bfloat16(v.y);
    o[2] = __float2bfloat16(v.z); o[3] = __float2bfloat16(v.w);
    *reinterpret_cast<uint2*>(d + i) = *reinterpret_cast<const uint2*>(o);
}

// ---------------------------------------------------------------------------
// Transpose f32 (R x C) -> bf16 (C x R). Dims multiples of 32.
// ---------------------------------------------------------------------------
__global__ __launch_bounds__(256) void transpose_f32_bf16(
    const float* __restrict__ src, __hip_bfloat16* __restrict__ dst,
    int R, int C)
{
    __shared__ __hip_bfloat16 tile[32][34];
    int c0 = blockIdx.x * 32, r0 = blockIdx.y * 32;
    int lx = threadIdx.x & 31, ly = threadIdx.x >> 5;
#pragma unroll
    for (int i = 0; i < 4; ++i)
        tile[ly + 8*i][lx] = __float2bfloat16(src[(size_t)(r0 + ly + 8*i) * C + c0 + lx]);
    __syncthreads();
#pragma unroll
    for (int i = 0; i < 4; ++i)
        dst[(size_t)(c0 + ly + 8*i) * R + r0 + lx] = tile[lx][ly + 8*i];
}

// ---------------------------------------------------------------------------
// MFMA bf16 GEMM: C = A @ B, B given TRANSPOSED as BT[N,K].
// 128x128 block tile, 4 waves. SK-way split-K via blockIdx.z.
// EPI 0: bf16 -> C0 (stride N).
// EPI 1: cols<DI: f16 softplus(+bias) -> C0 (stride DI);
//        cols DI..DI+31: f32 -> C1 (stride 32); cols >=DI+32: discard.
// EPI 2: f32 -> C0/C1/C2 by blockIdx.z (stride N).
// ---------------------------------------------------------------------------
template <int EPI, int SK>
__global__ __launch_bounds__(256) void gemm_bf16(
    const __hip_bfloat16* __restrict__ A,
    const __hip_bfloat16* __restrict__ BT,
    void* __restrict__ C0, void* __restrict__ C1, void* __restrict__ C2,
    const float* __restrict__ bias,
    int M, int N, int K)
{
    __shared__ __hip_bfloat16 As[128][32];   // byte offset of As[sr][sc] = tid*16
    __shared__ __hip_bfloat16 Bs[128][32];

    int tid  = threadIdx.x;
    int wave = tid >> 6, lane = tid & 63;
    int quad = lane >> 4, lr = lane & 15;
    int wm = (wave >> 1) * 64, wn = (wave & 1) * 64;
    int bm = blockIdx.x * 128, bn = blockIdx.y * 128;

    floatx4 acc[4][4];
#pragma unroll
    for (int i = 0; i < 4; ++i)
#pragma unroll
        for (int j = 0; j < 4; ++j)
            acc[i][j] = (floatx4){0.f, 0.f, 0.f, 0.f};

    int sr = tid >> 2;              // 0..63
    int sc = (tid & 3) * 8;         // 0,8,16,24

    int Klen  = K / SK;
    int kbase = (SK > 1) ? (int)blockIdx.z * Klen : 0;

    const __hip_bfloat16* gA0 = A  + (size_t)(bm + sr)      * K + sc;
    const __hip_bfloat16* gA1 = A  + (size_t)(bm + sr + 64) * K + sc;
    const __hip_bfloat16* gB0 = BT + (size_t)(bn + sr)      * K + sc;
    const __hip_bfloat16* gB1 = BT + (size_t)(bn + sr + 64) * K + sc;
    __hip_bfloat16* lA0 = &As[sr][sc];
    __hip_bfloat16* lA1 = &As[sr + 64][sc];
    __hip_bfloat16* lB0 = &Bs[sr][sc];
    __hip_bfloat16* lB1 = &Bs[sr + 64][sc];

    for (int k0 = kbase; k0 < kbase + Klen; k0 += 32) {
        async_cp16(gA0 + k0, lA0);
        async_cp16(gA1 + k0, lA1);
        async_cp16(gB0 + k0, lB0);
        async_cp16(gB1 + k0, lB1);
        __syncthreads();

        short8 afrag[4], bfrag[4];
#pragma unroll
        for (int i = 0; i < 4; ++i)
            afrag[i] = *reinterpret_cast<const short8*>(&As[wm + i*16 + lr][quad*8]);
#pragma unroll
        for (int j = 0; j < 4; ++j)
            bfrag[j] = *reinterpret_cast<const short8*>(&Bs[wn + j*16 + lr][quad*8]);
#pragma unroll
        for (int i = 0; i < 4; ++i)
#pragma unroll
            for (int j = 0; j < 4; ++j)
                acc[i][j] = __builtin_amdgcn_mfma_f32_16x16x32_bf16(
                    afrag[i], bfrag[j], acc[i][j], 0, 0, 0);
        __syncthreads();
    }

    float* skOut = nullptr;
    if (EPI == 2)
        skOut = (SK == 1) ? (float*)C0
              : (blockIdx.z == 0 ? (float*)C0 : blockIdx.z == 1 ? (float*)C1 : (float*)C2);

    // epilogue: within 16x16 tile, row = quad*4 + rr, col = lr
#pragma unroll
    for (int i = 0; i < 4; ++i) {
#pragma unroll
        for (int j = 0; j < 4; ++j) {
            int r0 = bm + wm + i*16 + quad*4;
            int c  = bn + wn + j*16 + lr;
#pragma unroll
            for (int rr = 0; rr < 4; ++rr) {
                float v = acc[i][j][rr];
                if (EPI == 0) {
                    ((__hip_bfloat16*)C0)[(size_t)(r0 + rr) * N + c] = __float2bfloat16(v);
                } else if (EPI == 1) {
                    if (c < DI) {
                        v += bias[c];
                        float sp = (v > 20.f) ? v : log1pf(__expf(v));
                        ((__half*)C0)[(size_t)(r0 + rr) * DI + c] = __float2half(sp);
                    } else if (c < DI + 32) {
                        ((float*)C1)[(size_t)(r0 + rr) * 32 + (c - DI)] = v;
                    } // else: padding column, discard
                } else {
                    skOut[(size_t)(r0 + rr) * N + c] = v;
                }
            }
        }
    }
}

// ---------------------------------------------------------------------------
// d += p1 + p2 (split-K reduce), float4 per thread.
// ---------------------------------------------------------------------------
__global__ __launch_bounds__(256) void add3(
    float* __restrict__ d, const float* __restrict__ p1, const float* __restrict__ p2)
{
    int i = (blockIdx.x * 256 + threadIdx.x) * 4;
    float4 a = *reinterpret_cast<float4*>(d + i);
    float4 b = *reinterpret_cast<const float4*>(p1 + i);
    float4 c = *reinterpret_cast<const float4*>(p2 + i);
    a.x += b.x + c.x; a.y += b.y + c.y; a.z += b.z + c.z; a.w += b.w + c.w;
    *reinterpret_cast<float4*>(d + i) = a;
}

// ---------------------------------------------------------------------------
// Depthwise causal conv (k=4) + bias + SiLU.
// ---------------------------------------------------------------------------
__global__ __launch_bounds__(256) void conv_silu(
    const __hip_bfloat16* __restrict__ xz,
    const float* __restrict__ Wc,
    const float* __restrict__ bc,
    __hip_bfloat16* __restrict__ xc)
{
    int idx = blockIdx.x * 256 + threadIdx.x;      // over ML*DI
    int d = idx % DI;
    int m = idx / DI;                              // m = b*LL + t
    int t = m % LL;
    float acc = bc[d];
#pragma unroll
    for (int j = 0; j < 4; ++j) {
        int tt = t - 3 + j;
        if (tt >= 0)
            acc += bf2f(xz[(size_t)(m - 3 + j) * (2*DI) + d]) * Wc[d*4 + j];
    }
    float s = acc / (1.f + __expf(-acc));
    xc[idx] = __float2bfloat16(s);
}

// ---------------------------------------------------------------------------
// Chunked scan, thread-per-(d, 4 states).  32 chunks x 64 steps.
// ---------------------------------------------------------------------------
__global__ __launch_bounds__(256) void scan_phaseA(
    const __half* __restrict__ dt, const __hip_bfloat16* __restrict__ xc,
    const float* __restrict__ BC, const float* __restrict__ A_log,
    __half* __restrict__ aprod, __half* __restrict__ hend)
{
    int idx = blockIdx.x * 256 + threadIdx.x;   // over DI*4 = 6144
    int q = idx & 3, d = idx >> 2;
    int c = blockIdx.y, b = blockIdx.z;
    float A4[4], h[4], ap[4];
#pragma unroll
    for (int j = 0; j < 4; ++j) {
        A4[j] = -__expf(A_log[d*DS + q*4 + j]);
        h[j] = 0.f; ap[j] = 1.f;
    }
    int t0 = c * CLEN;
    for (int t = t0; t < t0 + CLEN; ++t) {
        size_t row = (size_t)b * LL + t;
        float dtv = __half2float(dt[row * DI + d]);
        float xcv = bf2f(xc[row * DI + d]);
        float4 B4 = *reinterpret_cast<const float4*>(BC + row * 32 + q*4);
        float dtx = dtv * xcv;
#pragma unroll
        for (int j = 0; j < 4; ++j) {
            float dA = __expf(dtv * A4[j]);
            h[j]  = dA * h[j] + ((const float*)&B4)[j] * dtx;
            ap[j] *= dA;
        }
    }
    size_t o = (((size_t)b * NCHUNK + c) * DI + d) * DS + q*4;
    __half oa[4], oh[4];
#pragma unroll
    for (int j = 0; j < 4; ++j) { oa[j] = __float2half(ap[j]); oh[j] = __float2half(h[j]); }
    *reinterpret_cast<uint2*>(aprod + o) = *reinterpret_cast<const uint2*>(oa);
    *reinterpret_cast<uint2*>(hend  + o) = *reinterpret_cast<const uint2*>(oh);
}

__global__ __launch_bounds__(256) void scan_phaseB(
    const __half* __restrict__ aprod, __half* __restrict__ hse)
{
    int idx = blockIdx.x * 256 + threadIdx.x;   // over BB*DI*DS
    int b = idx / (DI*DS);
    int dn = idx % (DI*DS);
    float H = 0.f;
#pragma unroll
    for (int c = 0; c < NCHUNK; ++c) {
        size_t o = ((size_t)b * NCHUNK + c) * (DI*DS) + dn;
        float a  = __half2float(aprod[o]);
        float he = __half2float(hse[o]);
        hse[o] = __float2half(H);          // becomes hstart for chunk c
        H = a * H + he;
    }
}

__global__ __launch_bounds__(256) void scan_phaseC(
    const __half* __restrict__ dt, const __hip_bfloat16* __restrict__ xz,
    const float* __restrict__ BC, const float* __restrict__ A_log,
    const float* __restrict__ Dv, const __half* __restrict__ hstart,
    __hip_bfloat16* __restrict__ xc_y /* xc in, y out (in place) */)
{
    int idx = blockIdx.x * 256 + threadIdx.x;   // over DI*4 = 6144
    int q = idx & 3, d = idx >> 2;
    int c = blockIdx.y, b = blockIdx.z;
    float A4[4], h[4];
#pragma unroll
    for (int j = 0; j < 4; ++j)
        A4[j] = -__expf(A_log[d*DS + q*4 + j]);
    float Dd = Dv[d];
    size_t o = (((size_t)b * NCHUNK + c) * DI + d) * DS + q*4;
    {
        uint2 tmp = *reinterpret_cast<const uint2*>(hstart + o);
        const __half* hp = reinterpret_cast<const __half*>(&tmp);
#pragma unroll
        for (int j = 0; j < 4; ++j) h[j] = __half2float(hp[j]);
    }
    int t0 = c * CLEN;
    for (int t = t0; t < t0 + CLEN; ++t) {
        size_t row = (size_t)b * LL + t;
        float dtv = __half2float(dt[row * DI + d]);
        float xcv = bf2f(xc_y[row * DI + d]);       // read BEFORE the masked write
        float zv  = bf2f(xz[row * (2*DI) + DI + d]);
        float4 B4 = *reinterpret_cast<const float4*>(BC + row * 32 + q*4);
        float4 C4 = *reinterpret_cast<const float4*>(BC + row * 32 + 16 + q*4);
        float dtx = dtv * xcv;
        float ys = 0.f;
#pragma unroll
        for (int j = 0; j < 4; ++j) {
            float dA = __expf(dtv * A4[j]);
            h[j] = dA * h[j] + ((const float*)&B4)[j] * dtx;
            ys = fmaf(h[j], ((const float*)&C4)[j], ys);
        }
        ys += __shfl_xor(ys, 1);
        ys += __shfl_xor(ys, 2);
        if (q == 0) {
            float sig = 1.f / (1.f + __expf(-zv));
            float out = (ys + xcv * Dd) * (zv * sig);
            xc_y[row * DI + d] = __float2bfloat16(out);
        }
    }
}

// ---------------------------------------------------------------------------
extern "C" void kernel_launch(void* const* d_in, const int* in_sizes, int n_in,
                              void* d_out, int out_size, void* d_ws, size_t ws_size,
                              hipStream_t stream)
{
    const float* x      = (const float*)d_in[0];
    const float* W_in   = (const float*)d_in[1];
    const float* W_conv = (const float*)d_in[2];
    const float* b_conv = (const float*)d_in[3];
    const float* W_x    = (const float*)d_in[4];
    const float* W_dt   = (const float*)d_in[5];
    const float* b_dt   = (const float*)d_in[6];
    const float* A_log  = (const float*)d_in[7];
    const float* Dvec   = (const float*)d_in[8];
    const float* W_out  = (const float*)d_in[9];

    // ---- workspace layout (62.26 MiB, explicit lifetime reuse) ----
    uint8_t* ws = (uint8_t*)d_ws;
    __hip_bfloat16* xz     = (__hip_bfloat16*)(ws);               // 25,165,824 [G1..phaseC]
    float*          p1     = (float*)(ws);                        // 12,582,912 [G4..add3] (over xz)
    float*          p2     = (float*)(ws + 12582912);             // 12,582,912 [G4..add3] (over xz)
    __hip_bfloat16* winT   = (__hip_bfloat16*)(ws + 25165824);    //  4,718,592 [T1..G1]
    __half*         aprod  = (__half*)(ws + 25165824);            //  3,145,728 [phA..phB] (over winT)
    __half*         hse    = (__half*)(ws + 28311552);            //  3,145,728 [phA..phC] (over winT)
    __hip_bfloat16* wcombT = (__hip_bfloat16*)(ws + 31457280);    //  5,111,808 [T2..dtG]  (NDT x DI; rows 1568+ unwritten)
    __hip_bfloat16* woutT  = (__hip_bfloat16*)(ws + 31457280);    //  2,359,296 [T3..G4]   (over wcombT, after dtG)
    __hip_bfloat16* xcb    = (__hip_bfloat16*)(ws + 36569088);    // 12,582,912 [conv..G4], y in place
    __half*         dtb    = (__half*)(ws + 49152000);            // 12,582,912 [dtG..phaseC]
    __hip_bfloat16* xbf    = (__hip_bfloat16*)(ws + 49152000);    //  6,291,456 [cvt..G1]  (over dtb)
    float*          BC     = (float*)(ws + 61734912);             //    524,288 [dtG..phaseC]
    // end: 62,259,200 bytes

    // input conversions / weight transposes (f32 -> bf16, B^T layout)
    cvt_f32_bf16<<<(ML*DM)/1024, 256, 0, stream>>>(x, xbf);
    transpose_f32_bf16<<<dim3(2*DI/32, DM/32), 256, 0, stream>>>(W_in, winT, DM, 2*DI);
    transpose_f32_bf16<<<dim3(DI/32,   DI/32), 256, 0, stream>>>(W_dt, wcombT, DI, DI);
    transpose_f32_bf16<<<dim3(1,       DI/32), 256, 0, stream>>>(W_x,  wcombT + (size_t)DI*DI, DI, 32);

    // GEMM1: xz = x @ W_in     (4096 x 3072 x 768)
    gemm_bf16<0,1><<<dim3(ML/128, (2*DI)/128), 256, 0, stream>>>(
        xbf, winT, xz, nullptr, nullptr, nullptr, ML, 2*DI, DM);

    // conv + SiLU -> xc
    conv_silu<<<(ML*DI)/256, 256, 0, stream>>>(xz, W_conv, b_conv, xcb);

    // fused: dt = softplus(xc @ W_dt + b_dt) -> f16  AND  BC = xc @ W_x -> f32
    gemm_bf16<1,1><<<dim3(ML/128, NDT/128), 256, 0, stream>>>(
        xcb, wcombT, dtb, BC, nullptr, b_dt, ML, NDT, DI);

    // W_out transpose (after dtG: overlays wcombT)
    transpose_f32_bf16<<<dim3(DM/32, DI/32), 256, 0, stream>>>(W_out, woutT, DI, DM);

    // chunked scan + fused gating (y written over xcb)
    scan_phaseA<<<dim3(DI*4/256, NCHUNK, BB), 256, 0, stream>>>(dtb, xcb, BC, A_log, aprod, hse);
    scan_phaseB<<<(BB*DI*DS)/256, 256, 0, stream>>>(aprod, hse);
    scan_phaseC<<<dim3(DI*4/256, NCHUNK, BB), 256, 0, stream>>>(dtb, xz, BC, A_log, Dvec, hse, xcb);

    // out = y @ W_out  (4096 x 768 x 1536), split-K=3 -> d_out,p1,p2; reduce
    gemm_bf16<2,3><<<dim3(ML/128, DM/128, 3), 256, 0, stream>>>(
        xcb, woutT, d_out, p1, p2, nullptr, ML, DM, DI);
    add3<<<(ML*DM)/1024, 256, 0, stream>>>((float*)d_out, p1, p2);

    (void)in_sizes; (void)n_in; (void)out_size; (void)ws_size;
}

// Round 8
// 334.426 us; speedup vs baseline: 1.2929x; 1.0601x over previous
//
#include <hip/hip_runtime.h>
#include <hip/hip_bf16.h>
#include <hip/hip_fp16.h>
#include <math.h>

#define DI 1536
#define DM 768
#define DS 16
#define BB 2
#define LL 2048
#define ML (BB*LL)          /* 4096 rows */
#define NCHUNK 32
#define CLEN (LL/NCHUNK)    /* 64 */
#define NDT 1600            /* dt-GEMM tiled N: 1536 dt + 32 BC + 32 discard */

using short8  = __attribute__((ext_vector_type(8))) short;
using floatx4 = __attribute__((ext_vector_type(4))) float;

__device__ __forceinline__ float bf2f(__hip_bfloat16 v) { return __bfloat162float(v); }

// async global->LDS copy, 16 B per lane (LDS dest lane-contiguous).
__device__ __forceinline__ void async_cp16(const void* g, void* l)
{
    __builtin_amdgcn_global_load_lds(
        (const __attribute__((address_space(1))) unsigned int*)g,
        (__attribute__((address_space(3))) unsigned int*)l,
        16, 0, 0);
}

// ---------------------------------------------------------------------------
__global__ __launch_bounds__(256) void cvt_f32_bf16(
    const float* __restrict__ s, __hip_bfloat16* __restrict__ d)
{
    int i = (blockIdx.x * 256 + threadIdx.x) * 4;
    float4 v = *reinterpret_cast<const float4*>(s + i);
    __hip_bfloat16 o[4];
    o[0] = __float2bfloat16(v.x); o[1] = __float2bfloat16(v.y);
    o[2] = __float2bfloat16(v.z); o[3] = __float2bfloat16(v.w);
    *reinterpret_cast<uint2*>(d + i) = *reinterpret_cast<const uint2*>(o);
}

// ---------------------------------------------------------------------------
// Transpose f32 (R x C) -> bf16 (C x R). Dims multiples of 32.
// ---------------------------------------------------------------------------
__global__ __launch_bounds__(256) void transpose_f32_bf16(
    const float* __restrict__ src, __hip_bfloat16* __restrict__ dst,
    int R, int C)
{
    __shared__ __hip_bfloat16 tile[32][34];
    int c0 = blockIdx.x * 32, r0 = blockIdx.y * 32;
    int lx = threadIdx.x & 31, ly = threadIdx.x >> 5;
#pragma unroll
    for (int i = 0; i < 4; ++i)
        tile[ly + 8*i][lx] = __float2bfloat16(src[(size_t)(r0 + ly + 8*i) * C + c0 + lx]);
    __syncthreads();
#pragma unroll
    for (int i = 0; i < 4; ++i)
        dst[(size_t)(c0 + ly + 8*i) * R + r0 + lx] = tile[lx][ly + 8*i];
}

// ---------------------------------------------------------------------------
// MFMA bf16 GEMM, 128x128 tile: C = A @ B, B given TRANSPOSED as BT[N,K].
// EPI 0: bf16 -> C0 (stride N).  EPI 2: f32 -> C0/C1/C2 by blockIdx.z.
// ---------------------------------------------------------------------------
template <int EPI, int SK>
__global__ __launch_bounds__(256) void gemm_bf16(
    const __hip_bfloat16* __restrict__ A,
    const __hip_bfloat16* __restrict__ BT,
    void* __restrict__ C0, void* __restrict__ C1, void* __restrict__ C2,
    int M, int N, int K)
{
    __shared__ __hip_bfloat16 As[128][32];   // byte offset of As[sr][sc] = tid*16
    __shared__ __hip_bfloat16 Bs[128][32];

    int tid  = threadIdx.x;
    int wave = tid >> 6, lane = tid & 63;
    int quad = lane >> 4, lr = lane & 15;
    int wm = (wave >> 1) * 64, wn = (wave & 1) * 64;
    int bm = blockIdx.x * 128, bn = blockIdx.y * 128;

    floatx4 acc[4][4];
#pragma unroll
    for (int i = 0; i < 4; ++i)
#pragma unroll
        for (int j = 0; j < 4; ++j)
            acc[i][j] = (floatx4){0.f, 0.f, 0.f, 0.f};

    int sr = tid >> 2;              // 0..63
    int sc = (tid & 3) * 8;         // 0,8,16,24

    int Klen  = K / SK;
    int kbase = (SK > 1) ? (int)blockIdx.z * Klen : 0;

    const __hip_bfloat16* gA0 = A  + (size_t)(bm + sr)      * K + sc;
    const __hip_bfloat16* gA1 = A  + (size_t)(bm + sr + 64) * K + sc;
    const __hip_bfloat16* gB0 = BT + (size_t)(bn + sr)      * K + sc;
    const __hip_bfloat16* gB1 = BT + (size_t)(bn + sr + 64) * K + sc;
    __hip_bfloat16* lA0 = &As[sr][sc];
    __hip_bfloat16* lA1 = &As[sr + 64][sc];
    __hip_bfloat16* lB0 = &Bs[sr][sc];
    __hip_bfloat16* lB1 = &Bs[sr + 64][sc];

    for (int k0 = kbase; k0 < kbase + Klen; k0 += 32) {
        async_cp16(gA0 + k0, lA0);
        async_cp16(gA1 + k0, lA1);
        async_cp16(gB0 + k0, lB0);
        async_cp16(gB1 + k0, lB1);
        __syncthreads();

        short8 afrag[4], bfrag[4];
#pragma unroll
        for (int i = 0; i < 4; ++i)
            afrag[i] = *reinterpret_cast<const short8*>(&As[wm + i*16 + lr][quad*8]);
#pragma unroll
        for (int j = 0; j < 4; ++j)
            bfrag[j] = *reinterpret_cast<const short8*>(&Bs[wn + j*16 + lr][quad*8]);
#pragma unroll
        for (int i = 0; i < 4; ++i)
#pragma unroll
            for (int j = 0; j < 4; ++j)
                acc[i][j] = __builtin_amdgcn_mfma_f32_16x16x32_bf16(
                    afrag[i], bfrag[j], acc[i][j], 0, 0, 0);
        __syncthreads();
    }

    float* skOut = nullptr;
    if (EPI == 2)
        skOut = (SK == 1) ? (float*)C0
              : (blockIdx.z == 0 ? (float*)C0 : blockIdx.z == 1 ? (float*)C1 : (float*)C2);

    // epilogue: within 16x16 tile, row = quad*4 + rr, col = lr
#pragma unroll
    for (int i = 0; i < 4; ++i) {
#pragma unroll
        for (int j = 0; j < 4; ++j) {
            int r0 = bm + wm + i*16 + quad*4;
            int c  = bn + wn + j*16 + lr;
#pragma unroll
            for (int rr = 0; rr < 4; ++rr) {
                float v = acc[i][j][rr];
                if (EPI == 0) {
                    ((__hip_bfloat16*)C0)[(size_t)(r0 + rr) * N + c] = __float2bfloat16(v);
                } else {
                    skOut[(size_t)(r0 + rr) * N + c] = v;
                }
            }
        }
    }
}

// ---------------------------------------------------------------------------
// dt-GEMM, 128x64 tile (higher blocks/CU for the grid-starved shape).
// B^T = [W_dt^T ; W_x^T ; pad] (NDT x K).  cols<DI: softplus(+bias) -> f16 dt;
// cols DI..DI+31: f32 -> BC; cols >= DI+32: discard.
// ---------------------------------------------------------------------------
__global__ __launch_bounds__(256) void gemm_dt(
    const __hip_bfloat16* __restrict__ A,
    const __hip_bfloat16* __restrict__ BT,
    __half* __restrict__ dtb, float* __restrict__ BC,
    const float* __restrict__ bias,
    int M, int K)
{
    __shared__ __hip_bfloat16 As[128][32];   // 8 KB, byte off = tid*16
    __shared__ __hip_bfloat16 Bs[64][32];    // 4 KB, byte off = tid*16

    int tid  = threadIdx.x;
    int wave = tid >> 6, lane = tid & 63;
    int quad = lane >> 4, lr = lane & 15;
    int wm = (wave >> 1) * 64, wn = (wave & 1) * 32;
    int bm = blockIdx.x * 128, bn = blockIdx.y * 64;

    floatx4 acc[4][2];
#pragma unroll
    for (int i = 0; i < 4; ++i)
#pragma unroll
        for (int j = 0; j < 2; ++j)
            acc[i][j] = (floatx4){0.f, 0.f, 0.f, 0.f};

    int sr = tid >> 2;              // 0..63
    int sc = (tid & 3) * 8;

    const __hip_bfloat16* gA0 = A  + (size_t)(bm + sr)      * K + sc;
    const __hip_bfloat16* gA1 = A  + (size_t)(bm + sr + 64) * K + sc;
    const __hip_bfloat16* gB0 = BT + (size_t)(bn + sr)      * K + sc;
    __hip_bfloat16* lA0 = &As[sr][sc];
    __hip_bfloat16* lA1 = &As[sr + 64][sc];
    __hip_bfloat16* lB0 = &Bs[sr][sc];

    for (int k0 = 0; k0 < K; k0 += 32) {
        async_cp16(gA0 + k0, lA0);
        async_cp16(gA1 + k0, lA1);
        async_cp16(gB0 + k0, lB0);
        __syncthreads();

        short8 afrag[4], bfrag[2];
#pragma unroll
        for (int i = 0; i < 4; ++i)
            afrag[i] = *reinterpret_cast<const short8*>(&As[wm + i*16 + lr][quad*8]);
#pragma unroll
        for (int j = 0; j < 2; ++j)
            bfrag[j] = *reinterpret_cast<const short8*>(&Bs[wn + j*16 + lr][quad*8]);
#pragma unroll
        for (int i = 0; i < 4; ++i)
#pragma unroll
            for (int j = 0; j < 2; ++j)
                acc[i][j] = __builtin_amdgcn_mfma_f32_16x16x32_bf16(
                    afrag[i], bfrag[j], acc[i][j], 0, 0, 0);
        __syncthreads();
    }

#pragma unroll
    for (int i = 0; i < 4; ++i) {
#pragma unroll
        for (int j = 0; j < 2; ++j) {
            int r0 = bm + wm + i*16 + quad*4;
            int c  = bn + wn + j*16 + lr;
#pragma unroll
            for (int rr = 0; rr < 4; ++rr) {
                float v = acc[i][j][rr];
                if (c < DI) {
                    v += bias[c];
                    float sp = (v > 20.f) ? v : log1pf(__expf(v));
                    dtb[(size_t)(r0 + rr) * DI + c] = __float2half(sp);
                } else if (c < DI + 32) {
                    BC[(size_t)(r0 + rr) * 32 + (c - DI)] = v;
                } // else discard
            }
        }
    }
}

// ---------------------------------------------------------------------------
// d += p1 + p2 (split-K reduce), float4 per thread.
// ---------------------------------------------------------------------------
__global__ __launch_bounds__(256) void add3(
    float* __restrict__ d, const float* __restrict__ p1, const float* __restrict__ p2)
{
    int i = (blockIdx.x * 256 + threadIdx.x) * 4;
    float4 a = *reinterpret_cast<float4*>(d + i);
    float4 b = *reinterpret_cast<const float4*>(p1 + i);
    float4 c = *reinterpret_cast<const float4*>(p2 + i);
    a.x += b.x + c.x; a.y += b.y + c.y; a.z += b.z + c.z; a.w += b.w + c.w;
    *reinterpret_cast<float4*>(d + i) = a;
}

// ---------------------------------------------------------------------------
// Depthwise causal conv (k=4) + bias + SiLU, 4 channels/thread.
// ---------------------------------------------------------------------------
__global__ __launch_bounds__(256) void conv_silu(
    const __hip_bfloat16* __restrict__ xz,
    const float* __restrict__ Wc,
    const float* __restrict__ bc,
    __hip_bfloat16* __restrict__ xc)
{
    int idx = blockIdx.x * 256 + threadIdx.x;      // over ML*DI/4
    int d = (idx % (DI/4)) * 4;
    int m = idx / (DI/4);                          // m = b*LL + t
    int t = m % LL;
    float4 b4 = *reinterpret_cast<const float4*>(bc + d);
    float acc[4] = {b4.x, b4.y, b4.z, b4.w};
    float4 w[4];
#pragma unroll
    for (int l = 0; l < 4; ++l)
        w[l] = *reinterpret_cast<const float4*>(Wc + (size_t)(d + l) * 4);
#pragma unroll
    for (int j = 0; j < 4; ++j) {
        if (t - 3 + j >= 0) {
            uint2 raw = *reinterpret_cast<const uint2*>(xz + (size_t)(m - 3 + j) * (2*DI) + d);
            __hip_bfloat16 xv[4];
            *reinterpret_cast<uint2*>(xv) = raw;
#pragma unroll
            for (int l = 0; l < 4; ++l)
                acc[l] += bf2f(xv[l]) * ((const float*)&w[l])[j];
        }
    }
    __hip_bfloat16 o[4];
#pragma unroll
    for (int l = 0; l < 4; ++l) {
        float s = acc[l] / (1.f + __expf(-acc[l]));
        o[l] = __float2bfloat16(s);
    }
    *reinterpret_cast<uint2*>(xc + (size_t)m * DI + d) = *reinterpret_cast<const uint2*>(o);
}

// ---------------------------------------------------------------------------
// Chunked scan, thread-per-(d, 4 states).  32 chunks x 64 steps.
// ---------------------------------------------------------------------------
__global__ __launch_bounds__(256) void scan_phaseA(
    const __half* __restrict__ dt, const __hip_bfloat16* __restrict__ xc,
    const float* __restrict__ BC, const float* __restrict__ A_log,
    __half* __restrict__ aprod, __half* __restrict__ hend)
{
    int idx = blockIdx.x * 256 + threadIdx.x;   // over DI*4 = 6144
    int q = idx & 3, d = idx >> 2;
    int c = blockIdx.y, b = blockIdx.z;
    float A4[4], h[4], ap[4];
#pragma unroll
    for (int j = 0; j < 4; ++j) {
        A4[j] = -__expf(A_log[d*DS + q*4 + j]);
        h[j] = 0.f; ap[j] = 1.f;
    }
    int t0 = c * CLEN;
    for (int t = t0; t < t0 + CLEN; ++t) {
        size_t row = (size_t)b * LL + t;
        float dtv = __half2float(dt[row * DI + d]);
        float xcv = bf2f(xc[row * DI + d]);
        float4 B4 = *reinterpret_cast<const float4*>(BC + row * 32 + q*4);
        float dtx = dtv * xcv;
#pragma unroll
        for (int j = 0; j < 4; ++j) {
            float dA = __expf(dtv * A4[j]);
            h[j]  = dA * h[j] + ((const float*)&B4)[j] * dtx;
            ap[j] *= dA;
        }
    }
    size_t o = (((size_t)b * NCHUNK + c) * DI + d) * DS + q*4;
    __half oa[4], oh[4];
#pragma unroll
    for (int j = 0; j < 4; ++j) { oa[j] = __float2half(ap[j]); oh[j] = __float2half(h[j]); }
    *reinterpret_cast<uint2*>(aprod + o) = *reinterpret_cast<const uint2*>(oa);
    *reinterpret_cast<uint2*>(hend  + o) = *reinterpret_cast<const uint2*>(oh);
}

__global__ __launch_bounds__(256) void scan_phaseB(
    const __half* __restrict__ aprod, __half* __restrict__ hse)
{
    int idx = blockIdx.x * 256 + threadIdx.x;   // over BB*DI*DS
    int b = idx / (DI*DS);
    int dn = idx % (DI*DS);
    float H = 0.f;
#pragma unroll
    for (int c = 0; c < NCHUNK; ++c) {
        size_t o = ((size_t)b * NCHUNK + c) * (DI*DS) + dn;
        float a  = __half2float(aprod[o]);
        float he = __half2float(hse[o]);
        hse[o] = __float2half(H);          // becomes hstart for chunk c
        H = a * H + he;
    }
}

__global__ __launch_bounds__(256) void scan_phaseC(
    const __half* __restrict__ dt, const __hip_bfloat16* __restrict__ xz,
    const float* __restrict__ BC, const float* __restrict__ A_log,
    const float* __restrict__ Dv, const __half* __restrict__ hstart,
    __hip_bfloat16* __restrict__ xc_y /* xc in, y out (in place) */)
{
    int idx = blockIdx.x * 256 + threadIdx.x;   // over DI*4 = 6144
    int q = idx & 3, d = idx >> 2;
    int c = blockIdx.y, b = blockIdx.z;
    float A4[4], h[4];
#pragma unroll
    for (int j = 0; j < 4; ++j)
        A4[j] = -__expf(A_log[d*DS + q*4 + j]);
    float Dd = Dv[d];
    size_t o = (((size_t)b * NCHUNK + c) * DI + d) * DS + q*4;
    {
        uint2 tmp = *reinterpret_cast<const uint2*>(hstart + o);
        const __half* hp = reinterpret_cast<const __half*>(&tmp);
#pragma unroll
        for (int j = 0; j < 4; ++j) h[j] = __half2float(hp[j]);
    }
    int t0 = c * CLEN;
    for (int t = t0; t < t0 + CLEN; ++t) {
        size_t row = (size_t)b * LL + t;
        float dtv = __half2float(dt[row * DI + d]);
        float xcv = bf2f(xc_y[row * DI + d]);       // read BEFORE the masked write
        float zv  = bf2f(xz[row * (2*DI) + DI + d]);
        float4 B4 = *reinterpret_cast<const float4*>(BC + row * 32 + q*4);
        float4 C4 = *reinterpret_cast<const float4*>(BC + row * 32 + 16 + q*4);
        float dtx = dtv * xcv;
        float ys = 0.f;
#pragma unroll
        for (int j = 0; j < 4; ++j) {
            float dA = __expf(dtv * A4[j]);
            h[j] = dA * h[j] + ((const float*)&B4)[j] * dtx;
            ys = fmaf(h[j], ((const float*)&C4)[j], ys);
        }
        ys += __shfl_xor(ys, 1);
        ys += __shfl_xor(ys, 2);
        if (q == 0) {
            float sig = 1.f / (1.f + __expf(-zv));
            float out = (ys + xcv * Dd) * (zv * sig);
            xc_y[row * DI + d] = __float2bfloat16(out);
        }
    }
}

// ---------------------------------------------------------------------------
extern "C" void kernel_launch(void* const* d_in, const int* in_sizes, int n_in,
                              void* d_out, int out_size, void* d_ws, size_t ws_size,
                              hipStream_t stream)
{
    const float* x      = (const float*)d_in[0];
    const float* W_in   = (const float*)d_in[1];
    const float* W_conv = (const float*)d_in[2];
    const float* b_conv = (const float*)d_in[3];
    const float* W_x    = (const float*)d_in[4];
    const float* W_dt   = (const float*)d_in[5];
    const float* b_dt   = (const float*)d_in[6];
    const float* A_log  = (const float*)d_in[7];
    const float* Dvec   = (const float*)d_in[8];
    const float* W_out  = (const float*)d_in[9];

    // ---- workspace layout (62.26 MiB, explicit lifetime reuse) ----
    uint8_t* ws = (uint8_t*)d_ws;
    __hip_bfloat16* xz     = (__hip_bfloat16*)(ws);               // 25,165,824 [G1..phaseC]
    float*          p1     = (float*)(ws);                        // 12,582,912 [G4..add3] (over xz)
    float*          p2     = (float*)(ws + 12582912);             // 12,582,912 [G4..add3] (over xz)
    __hip_bfloat16* winT   = (__hip_bfloat16*)(ws + 25165824);    //  4,718,592 [T1..G1]
    __half*         aprod  = (__half*)(ws + 25165824);            //  3,145,728 [phA..phB] (over winT)
    __half*         hse    = (__half*)(ws + 28311552);            //  3,145,728 [phA..phC] (over winT)
    __hip_bfloat16* wcombT = (__hip_bfloat16*)(ws + 31457280);    //  4,915,200 [T2..dtG]  (NDT x DI; rows 1568+ unwritten)
    __hip_bfloat16* woutT  = (__hip_bfloat16*)(ws + 31457280);    //  2,359,296 [T3..G4]   (over wcombT, after dtG)
    __hip_bfloat16* xcb    = (__hip_bfloat16*)(ws + 36569088);    // 12,582,912 [conv..G4], y in place
    __half*         dtb    = (__half*)(ws + 49152000);            // 12,582,912 [dtG..phaseC]
    __hip_bfloat16* xbf    = (__hip_bfloat16*)(ws + 49152000);    //  6,291,456 [cvt..G1]  (over dtb)
    float*          BC     = (float*)(ws + 61734912);             //    524,288 [dtG..phaseC]
    // end: 62,259,200 bytes

    // input conversions / weight transposes (f32 -> bf16, B^T layout)
    cvt_f32_bf16<<<(ML*DM)/1024, 256, 0, stream>>>(x, xbf);
    transpose_f32_bf16<<<dim3(2*DI/32, DM/32), 256, 0, stream>>>(W_in, winT, DM, 2*DI);
    transpose_f32_bf16<<<dim3(DI/32,   DI/32), 256, 0, stream>>>(W_dt, wcombT, DI, DI);
    transpose_f32_bf16<<<dim3(1,       DI/32), 256, 0, stream>>>(W_x,  wcombT + (size_t)DI*DI, DI, 32);

    // GEMM1: xz = x @ W_in     (4096 x 3072 x 768)
    gemm_bf16<0,1><<<dim3(ML/128, (2*DI)/128), 256, 0, stream>>>(
        xbf, winT, xz, nullptr, nullptr, ML, 2*DI, DM);

    // conv + SiLU -> xc
    conv_silu<<<(ML*DI/4)/256, 256, 0, stream>>>(xz, W_conv, b_conv, xcb);

    // fused: dt = softplus(xc @ W_dt + b_dt) -> f16  AND  BC = xc @ W_x -> f32
    // 128x64 tile: 800 blocks = 3.1 blocks/CU
    gemm_dt<<<dim3(ML/128, NDT/64), 256, 0, stream>>>(
        xcb, wcombT, dtb, BC, b_dt, ML, DI);

    // W_out transpose (after dtG: overlays wcombT)
    transpose_f32_bf16<<<dim3(DM/32, DI/32), 256, 0, stream>>>(W_out, woutT, DI, DM);

    // chunked scan + fused gating (y written over xcb)
    scan_phaseA<<<dim3(DI*4/256, NCHUNK, BB), 256, 0, stream>>>(dtb, xcb, BC, A_log, aprod, hse);
    scan_phaseB<<<(BB*DI*DS)/256, 256, 0, stream>>>(aprod, hse);
    scan_phaseC<<<dim3(DI*4/256, NCHUNK, BB), 256, 0, stream>>>(dtb, xz, BC, A_log, Dvec, hse, xcb);

    // out = y @ W_out  (4096 x 768 x 1536), split-K=3 -> d_out,p1,p2; reduce
    gemm_bf16<2,3><<<dim3(ML/128, DM/128, 3), 256, 0, stream>>>(
        xcb, woutT, d_out, p1, p2, ML, DM, DI);
    add3<<<(ML*DM)/1024, 256, 0, stream>>>((float*)d_out, p1, p2);

    (void)in_sizes; (void)n_in; (void)out_size; (void)ws_size;
}

// Round 9
// 316.121 us; speedup vs baseline: 1.3678x; 1.0579x over previous
//
#include <hip/hip_runtime.h>
#include <hip/hip_bf16.h>
#include <hip/hip_fp16.h>
#include <math.h>

#define DI 1536
#define DM 768
#define DS 16
#define BB 2
#define LL 2048
#define ML (BB*LL)          /* 4096 rows */
#define NCHUNK 32
#define CLEN (LL/NCHUNK)    /* 64 */
#define NDT 1600            /* dt-GEMM tiled N: 1536 dt + 32 BC + 32 discard */

using short8  = __attribute__((ext_vector_type(8))) short;
using floatx4 = __attribute__((ext_vector_type(4))) float;

__device__ __forceinline__ float bf2f(__hip_bfloat16 v) { return __bfloat162float(v); }

// async global->LDS copy, 16 B per lane (LDS dest lane-contiguous).
__device__ __forceinline__ void async_cp16(const void* g, void* l)
{
    __builtin_amdgcn_global_load_lds(
        (const __attribute__((address_space(1))) unsigned int*)g,
        (__attribute__((address_space(3))) unsigned int*)l,
        16, 0, 0);
}

// ---------------------------------------------------------------------------
__global__ __launch_bounds__(256) void cvt_f32_bf16(
    const float* __restrict__ s, __hip_bfloat16* __restrict__ d)
{
    int i = (blockIdx.x * 256 + threadIdx.x) * 4;
    float4 v = *reinterpret_cast<const float4*>(s + i);
    __hip_bfloat16 o[4];
    o[0] = __float2bfloat16(v.x); o[1] = __float2bfloat16(v.y);
    o[2] = __float2bfloat16(v.z); o[3] = __float2bfloat16(v.w);
    *reinterpret_cast<uint2*>(d + i) = *reinterpret_cast<const uint2*>(o);
}

// ---------------------------------------------------------------------------
// Transpose f32 (R x C) -> bf16 (C x R). Dims multiples of 32.
// ---------------------------------------------------------------------------
__global__ __launch_bounds__(256) void transpose_f32_bf16(
    const float* __restrict__ src, __hip_bfloat16* __restrict__ dst,
    int R, int C)
{
    __shared__ __hip_bfloat16 tile[32][34];
    int c0 = blockIdx.x * 32, r0 = blockIdx.y * 32;
    int lx = threadIdx.x & 31, ly = threadIdx.x >> 5;
#pragma unroll
    for (int i = 0; i < 4; ++i)
        tile[ly + 8*i][lx] = __float2bfloat16(src[(size_t)(r0 + ly + 8*i) * C + c0 + lx]);
    __syncthreads();
#pragma unroll
    for (int i = 0; i < 4; ++i)
        dst[(size_t)(c0 + ly + 8*i) * R + r0 + lx] = tile[lx][ly + 8*i];
}

// ---------------------------------------------------------------------------
// MFMA bf16 GEMM, 128x128 tile, BK=64 as two BK=32 panels (half the barrier
// drains; panel layout keeps global_load_lds lane-contiguity + same bank
// pattern as BK=32).  B given TRANSPOSED as BT[N,K].
// EPI 0: bf16 -> C0 (stride N).  EPI 2: f32 -> C0/C1/C2 by blockIdx.z.
// ---------------------------------------------------------------------------
template <int EPI, int SK>
__global__ __launch_bounds__(256) void gemm_bf16(
    const __hip_bfloat16* __restrict__ A,
    const __hip_bfloat16* __restrict__ BT,
    void* __restrict__ C0, void* __restrict__ C1, void* __restrict__ C2,
    int M, int N, int K)
{
    __shared__ __hip_bfloat16 As[2][128][32];   // per panel: byte off = tid*16
    __shared__ __hip_bfloat16 Bs[2][128][32];

    int tid  = threadIdx.x;
    int wave = tid >> 6, lane = tid & 63;
    int quad = lane >> 4, lr = lane & 15;
    int wm = (wave >> 1) * 64, wn = (wave & 1) * 64;
    int bm = blockIdx.x * 128, bn = blockIdx.y * 128;

    floatx4 acc[4][4];
#pragma unroll
    for (int i = 0; i < 4; ++i)
#pragma unroll
        for (int j = 0; j < 4; ++j)
            acc[i][j] = (floatx4){0.f, 0.f, 0.f, 0.f};

    int sr = tid >> 2;              // 0..63
    int sc = (tid & 3) * 8;         // 0,8,16,24

    int Klen  = K / SK;
    int kbase = (SK > 1) ? (int)blockIdx.z * Klen : 0;

    const __hip_bfloat16* gA0 = A  + (size_t)(bm + sr)      * K + sc;
    const __hip_bfloat16* gA1 = A  + (size_t)(bm + sr + 64) * K + sc;
    const __hip_bfloat16* gB0 = BT + (size_t)(bn + sr)      * K + sc;
    const __hip_bfloat16* gB1 = BT + (size_t)(bn + sr + 64) * K + sc;

    for (int k0 = kbase; k0 < kbase + Klen; k0 += 64) {
        async_cp16(gA0 + k0,      &As[0][sr][sc]);
        async_cp16(gA0 + k0 + 32, &As[1][sr][sc]);
        async_cp16(gA1 + k0,      &As[0][sr + 64][sc]);
        async_cp16(gA1 + k0 + 32, &As[1][sr + 64][sc]);
        async_cp16(gB0 + k0,      &Bs[0][sr][sc]);
        async_cp16(gB0 + k0 + 32, &Bs[1][sr][sc]);
        async_cp16(gB1 + k0,      &Bs[0][sr + 64][sc]);
        async_cp16(gB1 + k0 + 32, &Bs[1][sr + 64][sc]);
        __syncthreads();

#pragma unroll
        for (int p = 0; p < 2; ++p) {
            short8 afrag[4], bfrag[4];
#pragma unroll
            for (int i = 0; i < 4; ++i)
                afrag[i] = *reinterpret_cast<const short8*>(&As[p][wm + i*16 + lr][quad*8]);
#pragma unroll
            for (int j = 0; j < 4; ++j)
                bfrag[j] = *reinterpret_cast<const short8*>(&Bs[p][wn + j*16 + lr][quad*8]);
#pragma unroll
            for (int i = 0; i < 4; ++i)
#pragma unroll
                for (int j = 0; j < 4; ++j)
                    acc[i][j] = __builtin_amdgcn_mfma_f32_16x16x32_bf16(
                        afrag[i], bfrag[j], acc[i][j], 0, 0, 0);
        }
        __syncthreads();
    }

    float* skOut = nullptr;
    if (EPI == 2)
        skOut = (SK == 1) ? (float*)C0
              : (blockIdx.z == 0 ? (float*)C0 : blockIdx.z == 1 ? (float*)C1 : (float*)C2);

    // epilogue: within 16x16 tile, row = quad*4 + rr, col = lr
#pragma unroll
    for (int i = 0; i < 4; ++i) {
#pragma unroll
        for (int j = 0; j < 4; ++j) {
            int r0 = bm + wm + i*16 + quad*4;
            int c  = bn + wn + j*16 + lr;
#pragma unroll
            for (int rr = 0; rr < 4; ++rr) {
                float v = acc[i][j][rr];
                if (EPI == 0) {
                    ((__hip_bfloat16*)C0)[(size_t)(r0 + rr) * N + c] = __float2bfloat16(v);
                } else {
                    skOut[(size_t)(r0 + rr) * N + c] = v;
                }
            }
        }
    }
}

// ---------------------------------------------------------------------------
// dt-GEMM, 128x64 tile, BK=64 as two BK=32 panels.
// B^T = [W_dt^T ; W_x^T ; pad] (NDT x K).  cols<DI: softplus(+bias) -> f16 dt;
// cols DI..DI+31: f32 -> BC; cols >= DI+32: discard.
// ---------------------------------------------------------------------------
__global__ __launch_bounds__(256) void gemm_dt(
    const __hip_bfloat16* __restrict__ A,
    const __hip_bfloat16* __restrict__ BT,
    __half* __restrict__ dtb, float* __restrict__ BC,
    const float* __restrict__ bias,
    int M, int K)
{
    __shared__ __hip_bfloat16 As[2][128][32];   // 16 KB
    __shared__ __hip_bfloat16 Bs[2][64][32];    //  8 KB

    int tid  = threadIdx.x;
    int wave = tid >> 6, lane = tid & 63;
    int quad = lane >> 4, lr = lane & 15;
    int wm = (wave >> 1) * 64, wn = (wave & 1) * 32;
    int bm = blockIdx.x * 128, bn = blockIdx.y * 64;

    floatx4 acc[4][2];
#pragma unroll
    for (int i = 0; i < 4; ++i)
#pragma unroll
        for (int j = 0; j < 2; ++j)
            acc[i][j] = (floatx4){0.f, 0.f, 0.f, 0.f};

    int sr = tid >> 2;              // 0..63
    int sc = (tid & 3) * 8;

    const __hip_bfloat16* gA0 = A  + (size_t)(bm + sr)      * K + sc;
    const __hip_bfloat16* gA1 = A  + (size_t)(bm + sr + 64) * K + sc;
    const __hip_bfloat16* gB0 = BT + (size_t)(bn + sr)      * K + sc;

    for (int k0 = 0; k0 < K; k0 += 64) {
        async_cp16(gA0 + k0,      &As[0][sr][sc]);
        async_cp16(gA0 + k0 + 32, &As[1][sr][sc]);
        async_cp16(gA1 + k0,      &As[0][sr + 64][sc]);
        async_cp16(gA1 + k0 + 32, &As[1][sr + 64][sc]);
        async_cp16(gB0 + k0,      &Bs[0][sr][sc]);
        async_cp16(gB0 + k0 + 32, &Bs[1][sr][sc]);
        __syncthreads();

#pragma unroll
        for (int p = 0; p < 2; ++p) {
            short8 afrag[4], bfrag[2];
#pragma unroll
            for (int i = 0; i < 4; ++i)
                afrag[i] = *reinterpret_cast<const short8*>(&As[p][wm + i*16 + lr][quad*8]);
#pragma unroll
            for (int j = 0; j < 2; ++j)
                bfrag[j] = *reinterpret_cast<const short8*>(&Bs[p][wn + j*16 + lr][quad*8]);
#pragma unroll
            for (int i = 0; i < 4; ++i)
#pragma unroll
                for (int j = 0; j < 2; ++j)
                    acc[i][j] = __builtin_amdgcn_mfma_f32_16x16x32_bf16(
                        afrag[i], bfrag[j], acc[i][j], 0, 0, 0);
        }
        __syncthreads();
    }

#pragma unroll
    for (int i = 0; i < 4; ++i) {
#pragma unroll
        for (int j = 0; j < 2; ++j) {
            int r0 = bm + wm + i*16 + quad*4;
            int c  = bn + wn + j*16 + lr;
#pragma unroll
            for (int rr = 0; rr < 4; ++rr) {
                float v = acc[i][j][rr];
                if (c < DI) {
                    v += bias[c];
                    float sp = (v > 20.f) ? v : log1pf(__expf(v));
                    dtb[(size_t)(r0 + rr) * DI + c] = __float2half(sp);
                } else if (c < DI + 32) {
                    BC[(size_t)(r0 + rr) * 32 + (c - DI)] = v;
                } // else discard
            }
        }
    }
}

// ---------------------------------------------------------------------------
// d += p1 + p2 (split-K reduce), float4 per thread.
// ---------------------------------------------------------------------------
__global__ __launch_bounds__(256) void add3(
    float* __restrict__ d, const float* __restrict__ p1, const float* __restrict__ p2)
{
    int i = (blockIdx.x * 256 + threadIdx.x) * 4;
    float4 a = *reinterpret_cast<float4*>(d + i);
    float4 b = *reinterpret_cast<const float4*>(p1 + i);
    float4 c = *reinterpret_cast<const float4*>(p2 + i);
    a.x += b.x + c.x; a.y += b.y + c.y; a.z += b.z + c.z; a.w += b.w + c.w;
    *reinterpret_cast<float4*>(d + i) = a;
}

// ---------------------------------------------------------------------------
// Depthwise causal conv (k=4) + bias + SiLU, 4 channels/thread.
// ---------------------------------------------------------------------------
__global__ __launch_bounds__(256) void conv_silu(
    const __hip_bfloat16* __restrict__ xz,
    const float* __restrict__ Wc,
    const float* __restrict__ bc,
    __hip_bfloat16* __restrict__ xc)
{
    int idx = blockIdx.x * 256 + threadIdx.x;      // over ML*DI/4
    int d = (idx % (DI/4)) * 4;
    int m = idx / (DI/4);                          // m = b*LL + t
    int t = m % LL;
    float4 b4 = *reinterpret_cast<const float4*>(bc + d);
    float acc[4] = {b4.x, b4.y, b4.z, b4.w};
    float4 w[4];
#pragma unroll
    for (int l = 0; l < 4; ++l)
        w[l] = *reinterpret_cast<const float4*>(Wc + (size_t)(d + l) * 4);
#pragma unroll
    for (int j = 0; j < 4; ++j) {
        if (t - 3 + j >= 0) {
            uint2 raw = *reinterpret_cast<const uint2*>(xz + (size_t)(m - 3 + j) * (2*DI) + d);
            __hip_bfloat16 xv[4];
            *reinterpret_cast<uint2*>(xv) = raw;
#pragma unroll
            for (int l = 0; l < 4; ++l)
                acc[l] += bf2f(xv[l]) * ((const float*)&w[l])[j];
        }
    }
    __hip_bfloat16 o[4];
#pragma unroll
    for (int l = 0; l < 4; ++l) {
        float s = acc[l] / (1.f + __expf(-acc[l]));
        o[l] = __float2bfloat16(s);
    }
    *reinterpret_cast<uint2*>(xc + (size_t)m * DI + d) = *reinterpret_cast<const uint2*>(o);
}

// ---------------------------------------------------------------------------
// Chunked scan, thread-per-(d, 4 states).  32 chunks x 64 steps.
// ---------------------------------------------------------------------------
__global__ __launch_bounds__(256) void scan_phaseA(
    const __half* __restrict__ dt, const __hip_bfloat16* __restrict__ xc,
    const float* __restrict__ BC, const float* __restrict__ A_log,
    __half* __restrict__ aprod, __half* __restrict__ hend)
{
    int idx = blockIdx.x * 256 + threadIdx.x;   // over DI*4 = 6144
    int q = idx & 3, d = idx >> 2;
    int c = blockIdx.y, b = blockIdx.z;
    float A4[4], h[4], ap[4];
#pragma unroll
    for (int j = 0; j < 4; ++j) {
        A4[j] = -__expf(A_log[d*DS + q*4 + j]);
        h[j] = 0.f; ap[j] = 1.f;
    }
    int t0 = c * CLEN;
    for (int t = t0; t < t0 + CLEN; ++t) {
        size_t row = (size_t)b * LL + t;
        float dtv = __half2float(dt[row * DI + d]);
        float xcv = bf2f(xc[row * DI + d]);
        float4 B4 = *reinterpret_cast<const float4*>(BC + row * 32 + q*4);
        float dtx = dtv * xcv;
#pragma unroll
        for (int j = 0; j < 4; ++j) {
            float dA = __expf(dtv * A4[j]);
            h[j]  = dA * h[j] + ((const float*)&B4)[j] * dtx;
            ap[j] *= dA;
        }
    }
    size_t o = (((size_t)b * NCHUNK + c) * DI + d) * DS + q*4;
    __half oa[4], oh[4];
#pragma unroll
    for (int j = 0; j < 4; ++j) { oa[j] = __float2half(ap[j]); oh[j] = __float2half(h[j]); }
    *reinterpret_cast<uint2*>(aprod + o) = *reinterpret_cast<const uint2*>(oa);
    *reinterpret_cast<uint2*>(hend  + o) = *reinterpret_cast<const uint2*>(oh);
}

__global__ __launch_bounds__(256) void scan_phaseB(
    const __half* __restrict__ aprod, __half* __restrict__ hse)
{
    int idx = blockIdx.x * 256 + threadIdx.x;   // over BB*DI*DS
    int b = idx / (DI*DS);
    int dn = idx % (DI*DS);
    float H = 0.f;
#pragma unroll
    for (int c = 0; c < NCHUNK; ++c) {
        size_t o = ((size_t)b * NCHUNK + c) * (DI*DS) + dn;
        float a  = __half2float(aprod[o]);
        float he = __half2float(hse[o]);
        hse[o] = __float2half(H);          // becomes hstart for chunk c
        H = a * H + he;
    }
}

__global__ __launch_bounds__(256) void scan_phaseC(
    const __half* __restrict__ dt, const __hip_bfloat16* __restrict__ xz,
    const float* __restrict__ BC, const float* __restrict__ A_log,
    const float* __restrict__ Dv, const __half* __restrict__ hstart,
    __hip_bfloat16* __restrict__ xc_y /* xc in, y out (in place) */)
{
    int idx = blockIdx.x * 256 + threadIdx.x;   // over DI*4 = 6144
    int q = idx & 3, d = idx >> 2;
    int c = blockIdx.y, b = blockIdx.z;
    float A4[4], h[4];
#pragma unroll
    for (int j = 0; j < 4; ++j)
        A4[j] = -__expf(A_log[d*DS + q*4 + j]);
    float Dd = Dv[d];
    size_t o = (((size_t)b * NCHUNK + c) * DI + d) * DS + q*4;
    {
        uint2 tmp = *reinterpret_cast<const uint2*>(hstart + o);
        const __half* hp = reinterpret_cast<const __half*>(&tmp);
#pragma unroll
        for (int j = 0; j < 4; ++j) h[j] = __half2float(hp[j]);
    }
    int t0 = c * CLEN;
    for (int t = t0; t < t0 + CLEN; ++t) {
        size_t row = (size_t)b * LL + t;
        float dtv = __half2float(dt[row * DI + d]);
        float xcv = bf2f(xc_y[row * DI + d]);       // read BEFORE the masked write
        float zv  = bf2f(xz[row * (2*DI) + DI + d]);
        float4 B4 = *reinterpret_cast<const float4*>(BC + row * 32 + q*4);
        float4 C4 = *reinterpret_cast<const float4*>(BC + row * 32 + 16 + q*4);
        float dtx = dtv * xcv;
        float ys = 0.f;
#pragma unroll
        for (int j = 0; j < 4; ++j) {
            float dA = __expf(dtv * A4[j]);
            h[j] = dA * h[j] + ((const float*)&B4)[j] * dtx;
            ys = fmaf(h[j], ((const float*)&C4)[j], ys);
        }
        ys += __shfl_xor(ys, 1);
        ys += __shfl_xor(ys, 2);
        if (q == 0) {
            float sig = 1.f / (1.f + __expf(-zv));
            float out = (ys + xcv * Dd) * (zv * sig);
            xc_y[row * DI + d] = __float2bfloat16(out);
        }
    }
}

// ---------------------------------------------------------------------------
extern "C" void kernel_launch(void* const* d_in, const int* in_sizes, int n_in,
                              void* d_out, int out_size, void* d_ws, size_t ws_size,
                              hipStream_t stream)
{
    const float* x      = (const float*)d_in[0];
    const float* W_in   = (const float*)d_in[1];
    const float* W_conv = (const float*)d_in[2];
    const float* b_conv = (const float*)d_in[3];
    const float* W_x    = (const float*)d_in[4];
    const float* W_dt   = (const float*)d_in[5];
    const float* b_dt   = (const float*)d_in[6];
    const float* A_log  = (const float*)d_in[7];
    const float* Dvec   = (const float*)d_in[8];
    const float* W_out  = (const float*)d_in[9];

    // ---- workspace layout (62.26 MiB, explicit lifetime reuse) ----
    uint8_t* ws = (uint8_t*)d_ws;
    __hip_bfloat16* xz     = (__hip_bfloat16*)(ws);               // 25,165,824 [G1..phaseC]
    float*          p1     = (float*)(ws);                        // 12,582,912 [G4..add3] (over xz)
    float*          p2     = (float*)(ws + 12582912);             // 12,582,912 [G4..add3] (over xz)
    __hip_bfloat16* winT   = (__hip_bfloat16*)(ws + 25165824);    //  4,718,592 [T1..G1]
    __half*         aprod  = (__half*)(ws + 25165824);            //  3,145,728 [phA..phB] (over winT)
    __half*         hse    = (__half*)(ws + 28311552);            //  3,145,728 [phA..phC] (over winT)
    __hip_bfloat16* wcombT = (__hip_bfloat16*)(ws + 31457280);    //  4,915,200 [T2..dtG]  (NDT x DI; rows 1568+ unwritten)
    __hip_bfloat16* woutT  = (__hip_bfloat16*)(ws + 31457280);    //  2,359,296 [T3..G4]   (over wcombT, after dtG)
    __hip_bfloat16* xcb    = (__hip_bfloat16*)(ws + 36569088);    // 12,582,912 [conv..G4], y in place
    __half*         dtb    = (__half*)(ws + 49152000);            // 12,582,912 [dtG..phaseC]
    __hip_bfloat16* xbf    = (__hip_bfloat16*)(ws + 49152000);    //  6,291,456 [cvt..G1]  (over dtb)
    float*          BC     = (float*)(ws + 61734912);             //    524,288 [dtG..phaseC]
    // end: 62,259,200 bytes

    // input conversions / weight transposes (f32 -> bf16, B^T layout)
    cvt_f32_bf16<<<(ML*DM)/1024, 256, 0, stream>>>(x, xbf);
    transpose_f32_bf16<<<dim3(2*DI/32, DM/32), 256, 0, stream>>>(W_in, winT, DM, 2*DI);
    transpose_f32_bf16<<<dim3(DI/32,   DI/32), 256, 0, stream>>>(W_dt, wcombT, DI, DI);
    transpose_f32_bf16<<<dim3(1,       DI/32), 256, 0, stream>>>(W_x,  wcombT + (size_t)DI*DI, DI, 32);

    // GEMM1: xz = x @ W_in     (4096 x 3072 x 768)
    gemm_bf16<0,1><<<dim3(ML/128, (2*DI)/128), 256, 0, stream>>>(
        xbf, winT, xz, nullptr, nullptr, ML, 2*DI, DM);

    // conv + SiLU -> xc
    conv_silu<<<(ML*DI/4)/256, 256, 0, stream>>>(xz, W_conv, b_conv, xcb);

    // fused: dt = softplus(xc @ W_dt + b_dt) -> f16  AND  BC = xc @ W_x -> f32
    gemm_dt<<<dim3(ML/128, NDT/64), 256, 0, stream>>>(
        xcb, wcombT, dtb, BC, b_dt, ML, DI);

    // W_out transpose (after dtG: overlays wcombT)
    transpose_f32_bf16<<<dim3(DM/32, DI/32), 256, 0, stream>>>(W_out, woutT, DI, DM);

    // chunked scan + fused gating (y written over xcb)
    scan_phaseA<<<dim3(DI*4/256, NCHUNK, BB), 256, 0, stream>>>(dtb, xcb, BC, A_log, aprod, hse);
    scan_phaseB<<<(BB*DI*DS)/256, 256, 0, stream>>>(aprod, hse);
    scan_phaseC<<<dim3(DI*4/256, NCHUNK, BB), 256, 0, stream>>>(dtb, xz, BC, A_log, Dvec, hse, xcb);

    // out = y @ W_out  (4096 x 768 x 1536), split-K=3 -> d_out,p1,p2; reduce
    gemm_bf16<2,3><<<dim3(ML/128, DM/128, 3), 256, 0, stream>>>(
        xcb, woutT, d_out, p1, p2, ML, DM, DI);
    add3<<<(ML*DM)/1024, 256, 0, stream>>>((float*)d_out, p1, p2);

    (void)in_sizes; (void)n_in; (void)out_size; (void)ws_size;
}